// Round 9
// baseline (744.481 us; speedup 1.0000x reference)
//
#include <hip/hip_runtime.h>
#include <math.h>

#define N_NODES 20000
#define E_EDGES 160000
#define LAT 128
#define MUL 16
#define DD 9
#define TPD 48

// ---- workspace layout (float offsets) ----
#define WS_QB     ((size_t)0)
#define WS_KB     (WS_QB + (size_t)N_NODES*LAT/2)
#define WS_VB     (WS_KB + (size_t)N_NODES*LAT/2)
#define WS_SB     (WS_VB + (size_t)N_NODES*LAT/2)
#define WS_W48    (WS_SB + (size_t)N_NODES*LAT/2)         // bf16: E*48 ushorts
#define WS_SPATB  (WS_W48 + (size_t)E_EDGES*TPD)          // bf16: E*128 ushorts (spat, then o_t)
#define WS_ALPHA  (WS_SPATB + (size_t)E_EDGES*LAT/2)
#define WS_ZERO   (WS_ALPHA + (size_t)E_EDGES*4)
#define WS_AMAX   WS_ZERO
#define WS_DEN    (WS_AMAX + (size_t)N_NODES*4)
#define WS_HSUM   (WS_DEN + (size_t)N_NODES*4)            // bf16: N*128 ushorts
#define WS_NDX    (WS_HSUM + (size_t)N_NODES*LAT/2)       // bf16: N*144 ushorts
#define WS_END    (WS_NDX + (size_t)N_NODES*72)
#define ZERO_CNT  (WS_END - WS_ZERO)
#define WS_WB     WS_END                                   // ushort (bf16) packed weights
#define WS_XB     (WS_WB + (size_t)145408)                 // bf16 X table: N*144 ushorts

// packed weight offsets (ushort elements)
#define WOFF_WQ   0
#define WOFF_WK   16384
#define WOFF_GV1  32768
#define WOFF_GV2  49152
#define WOFF_GS1  65536
#define WOFF_GS2  81920
#define WOFF_GW1  98304
#define WOFF_GW2  106496
#define WOFF_GT1  122880
#define WOFF_GT2  139264
#define WOFF_WRS  155648
#define WOFF_WRE  172032
#define WOFF_GSP1 188416
#define WOFF_GSP2 204800
#define WOFF_MD1  253952
#define WOFF_MD2  270336
#define WOFF_MT1  272384
#define WOFF_MT2  288768
#define WB_TOTAL  290816

// k_prep block ranges
#define PREP_ZB   11250
#define PREP_PB   1136
#define PREP_XB   5625

#define DEVI __device__ __forceinline__

typedef short short8 __attribute__((ext_vector_type(8)));
typedef float f32x4 __attribute__((ext_vector_type(4)));

DEVI float silu_f(float x){ return x / (1.f + __expf(-x)); }
DEVI unsigned int fmap(float x){ unsigned int b=__float_as_uint(x); return (b&0x80000000u)? ~b : (b|0x80000000u); }
DEVI float funmap(unsigned int u){ return (u&0x80000000u)? __uint_as_float(u&0x7fffffffu) : __uint_as_float(~u); }

// branchless RNE f32->bf16 (proven fastest; hip_bf16 header versions carry NaN-select bloat)
DEVI unsigned short f2b(float f){ unsigned int u=__float_as_uint(f); return (unsigned short)((u + 0x7fffu + ((u>>16)&1u))>>16); }
DEVI unsigned int f2b2(float lo, float hi){ return ((unsigned int)f2b(hi)<<16) | (unsigned int)f2b(lo); }
DEVI float b2f(unsigned short u){ return __uint_as_float(((unsigned int)u)<<16); }

// packed bf16x2 fire-and-forget atomic add (gfx950)
DEVI void atom_pk(unsigned short* p, unsigned int pk){
  asm volatile("global_atomic_pk_add_bf16 %0, %1, off" :: "v"(p), "v"(pk) : "memory");
}

DEVI f32x4 mfma16(short8 a, short8 b, f32x4 c){
  return __builtin_amdgcn_mfma_f32_16x16x32_bf16(a,b,c,0,0,0);
}

template<int KB>
DEVI void mm_tile2(const unsigned short* act, int strideUS, const unsigned short* Wp,
                   int ntile, int m, int quad, f32x4* acc){
  const unsigned short* wp = Wp + (size_t)ntile*KB*512 + (size_t)quad*128 + m*8;
  const unsigned short* a0 = act + m*strideUS + quad*8;
  const unsigned short* a1 = a0 + 16*strideUS;
  #pragma unroll
  for (int kb=0;kb<KB;++kb){
    short8 bfr = *(const short8*)(wp + (size_t)kb*512);
    short8 af0 = *(const short8*)(a0 + kb*32);
    short8 af1 = *(const short8*)(a1 + kb*32);
    acc[0]=mfma16(af0,bfr,acc[0]);
    acc[1]=mfma16(af1,bfr,acc[1]);
  }
}

template<int KB>
DEVI void mm_tile1(const unsigned short* act, int strideUS, const unsigned short* Wp,
                   int mtbase, int m, int quad, f32x4& acc){
  const unsigned short* wp = Wp + (size_t)quad*128 + m*8;
  const unsigned short* a0 = act + (mtbase*16+m)*strideUS + quad*8;
  #pragma unroll
  for (int kb=0;kb<KB;++kb){
    short8 bfr = *(const short8*)(wp + (size_t)kb*512);
    short8 af  = *(const short8*)(a0 + kb*32);
    acc=mfma16(af,bfr,acc);
  }
}

template<int R, int KD, int LDSTRIDE>
DEVI void mm_acc(const float* src, const float* __restrict__ W, int wstride, int t, float* acc){
  #pragma unroll 2
  for (int k=0;k<KD;k+=4){
    float4 xv[R];
    #pragma unroll
    for (int r=0;r<R;++r) xv[r] = *(const float4*)(src + r*LDSTRIDE + k);
    #pragma unroll
    for (int kk=0;kk<4;++kk){
      float wk = W[(size_t)(k+kk)*wstride + t];
      #pragma unroll
      for (int r=0;r<R;++r) acc[r] += ((const float*)&xv[r])[kk]*wk;
    }
  }
}

// ---- K_prep: fused {zero accumulators | pack weights bf16 | X -> bf16 table} ----
__global__ __launch_bounds__(256) void k_prep(
  const float* __restrict__ X,
  const float* __restrict__ Wq,const float* __restrict__ Wk,
  const float* __restrict__ gv1,const float* __restrict__ gv2,
  const float* __restrict__ gs1,const float* __restrict__ gs2,
  const float* __restrict__ gw1,const float* __restrict__ gw2,
  const float* __restrict__ gt1,const float* __restrict__ gt2,
  const float* __restrict__ Wrs,const float* __restrict__ Wre,
  const float* __restrict__ gsp1,const float* __restrict__ gsp2,
  const float* __restrict__ md1,const float* __restrict__ md2,
  const float* __restrict__ mt1,const float* __restrict__ mt2,
  float* __restrict__ ws)
{
  const int b = blockIdx.x, tid = threadIdx.x;
  if (b < PREP_ZB){
    size_t i = (size_t)b*256 + tid;
    if (i < ZERO_CNT) ws[WS_ZERO + i] = 0.f;
    return;
  }
  if (b < PREP_ZB + PREP_PB){
    int i = (b - PREP_ZB)*256 + tid;
    if (i >= WB_TOTAL) return;
    unsigned short* dst = (unsigned short*)(ws + WS_WB);
    const int off[19] = {0,16384,32768,49152,65536,81920,98304,106496,122880,139264,
                         155648,172032,188416,204800,253952,270336,272384,288768,290816};
    int mi=0;
    while (i >= off[mi+1]) ++mi;
    int li = i - off[mi];
    int N = (mi==13)?384:((mi==15||mi==17)?16:128);
    int Ksrc = (mi==6)?48:128;
    int KB = (mi==6)?2:4;
    int j = li&7; int t = li>>3;
    int n_in = t&15; t>>=4;
    int quad = t&3; t>>=2;
    int k_block = t % KB; int n_tile = t / KB;
    int k = k_block*32 + quad*8 + j;
    int n = n_tile*16 + n_in;
    const float* src;
    switch(mi){
      case 0: src=Wq; break;  case 1: src=Wk; break;
      case 2: src=gv1; break; case 3: src=gv2; break;
      case 4: src=gs1; break; case 5: src=gs2; break;
      case 6: src=gw1; break; case 7: src=gw2; break;
      case 8: src=gt1; break; case 9: src=gt2; break;
      case 10: src=Wrs; break; case 11: src=Wre; break;
      case 12: src=gsp1; break; case 13: src=gsp2; break;
      case 14: src=md1; break; case 15: src=md2; break;
      default: src=(mi==16)?mt1:mt2; break;
    }
    float v = (k < Ksrc) ? src[(size_t)k*N + n] : 0.f;
    dst[i] = f2b(v);
    return;
  }
  {
    size_t idx = (size_t)(b - PREP_ZB - PREP_PB)*256 + tid;
    if (idx < (size_t)N_NODES*72){
      float2 v = *(const float2*)(X + idx*2);
      ((unsigned int*)(ws + WS_XB))[idx] = f2b2(v.x, v.y);
    }
    return;
  }
}

// ---- K1: per-node Q,K,V(gv),S(gs) via MFMA, 32 nodes/block; outputs bf16 ----
__global__ __launch_bounds__(256) void k1_node(const float* __restrict__ h,
  const unsigned short* __restrict__ WB,
  const float* __restrict__ Wq_b,const float* __restrict__ Wk_b,
  const float* __restrict__ gv_b1,const float* __restrict__ gv_b2,
  const float* __restrict__ gs_b1,const float* __restrict__ gs_b2,
  float* __restrict__ ws)
{
  __shared__ __align__(16) unsigned short B0[32*136], B1[32*136];
  const int tid=threadIdx.x, lane=tid&63, w=tid>>6, m=lane&15, quad=lane>>4;
  const int n0=blockIdx.x*32;
  for (int idx=tid; idx<1024; idx+=256){ int r=idx>>5, c4=(idx&31)*4;
    float4 hv = *(const float4*)(h+(size_t)(n0+r)*128+c4);
    *(unsigned int*)(B0+r*136+c4)   = f2b2(hv.x,hv.y);
    *(unsigned int*)(B0+r*136+c4+2) = f2b2(hv.z,hv.w); }
  __syncthreads();
  unsigned short* Qb=(unsigned short*)(ws+WS_QB);
  unsigned short* Kb=(unsigned short*)(ws+WS_KB);
  unsigned short* Vb=(unsigned short*)(ws+WS_VB);
  unsigned short* Sb=(unsigned short*)(ws+WS_SB);
  f32x4 z4 = {0.f,0.f,0.f,0.f};
  // Q
  { f32x4 acc[2][2]={{z4,z4},{z4,z4}};
    #pragma unroll
    for(int i=0;i<2;++i) mm_tile2<4>(B0,136,WB+WOFF_WQ, w*2+i, m, quad, acc[i]);
    #pragma unroll
    for(int i=0;i<2;++i){ int col=(w*2+i)*16+m; float bv=Wq_b[col];
      #pragma unroll
      for(int mt=0;mt<2;++mt)
        #pragma unroll
        for(int r=0;r<4;++r){ int row=mt*16+quad*4+r;
          Qb[(size_t)(n0+row)*128+col]=f2b(acc[i][mt][r]+bv); } } }
  // K
  { f32x4 acc[2][2]={{z4,z4},{z4,z4}};
    #pragma unroll
    for(int i=0;i<2;++i) mm_tile2<4>(B0,136,WB+WOFF_WK, w*2+i, m, quad, acc[i]);
    #pragma unroll
    for(int i=0;i<2;++i){ int col=(w*2+i)*16+m; float bv=Wk_b[col];
      #pragma unroll
      for(int mt=0;mt<2;++mt)
        #pragma unroll
        for(int r=0;r<4;++r){ int row=mt*16+quad*4+r;
          Kb[(size_t)(n0+row)*128+col]=f2b(acc[i][mt][r]+bv); } } }
  // gv hidden
  { f32x4 acc[2][2]={{z4,z4},{z4,z4}};
    #pragma unroll
    for(int i=0;i<2;++i) mm_tile2<4>(B0,136,WB+WOFF_GV1, w*2+i, m, quad, acc[i]);
    #pragma unroll
    for(int i=0;i<2;++i){ int col=(w*2+i)*16+m; float bv=gv_b1[col];
      #pragma unroll
      for(int mt=0;mt<2;++mt)
        #pragma unroll
        for(int r=0;r<4;++r) B1[(mt*16+quad*4+r)*136+col]=f2b(silu_f(acc[i][mt][r]+bv)); } }
  __syncthreads();
  // V out
  { f32x4 acc[2][2]={{z4,z4},{z4,z4}};
    #pragma unroll
    for(int i=0;i<2;++i) mm_tile2<4>(B1,136,WB+WOFF_GV2, w*2+i, m, quad, acc[i]);
    #pragma unroll
    for(int i=0;i<2;++i){ int col=(w*2+i)*16+m; float bv=gv_b2[col];
      #pragma unroll
      for(int mt=0;mt<2;++mt)
        #pragma unroll
        for(int r=0;r<4;++r){ int row=mt*16+quad*4+r;
          Vb[(size_t)(n0+row)*128+col]=f2b(acc[i][mt][r]+bv); } } }
  __syncthreads();
  // gs hidden
  { f32x4 acc[2][2]={{z4,z4},{z4,z4}};
    #pragma unroll
    for(int i=0;i<2;++i) mm_tile2<4>(B0,136,WB+WOFF_GS1, w*2+i, m, quad, acc[i]);
    #pragma unroll
    for(int i=0;i<2;++i){ int col=(w*2+i)*16+m; float bv=gs_b1[col];
      #pragma unroll
      for(int mt=0;mt<2;++mt)
        #pragma unroll
        for(int r=0;r<4;++r) B1[(mt*16+quad*4+r)*136+col]=f2b(silu_f(acc[i][mt][r]+bv)); } }
  __syncthreads();
  // S out
  { f32x4 acc[2][2]={{z4,z4},{z4,z4}};
    #pragma unroll
    for(int i=0;i<2;++i) mm_tile2<4>(B1,136,WB+WOFF_GS2, w*2+i, m, quad, acc[i]);
    #pragma unroll
    for(int i=0;i<2;++i){ int col=(w*2+i)*16+m; float bv=gs_b2[col];
      #pragma unroll
      for(int mt=0;mt<2;++mt)
        #pragma unroll
        for(int r=0;r<4;++r){ int row=mt*16+quad*4+r;
          Sb[(size_t)(n0+row)*128+col]=f2b(acc[i][mt][r]+bv); } } }
}

// ---- K2: per-edge w (eq_linear + rejection + slice dots) — bf16 X gathers ----
__global__ __launch_bounds__(256) void k2_edge_w(
  const float* __restrict__ sph,
  const float* __restrict__ Wtq, const float* __restrict__ Wtk,
  const int* __restrict__ ec, const int* __restrict__ en, float* __restrict__ ws)
{
  __shared__ unsigned short xcb[16*144], xnb[16*144];
  __shared__ float sphL[16][9];
  __shared__ float wq[768], wkk[768];
  __shared__ int ceI[16], nbI[16];
  const int tid=threadIdx.x, e0=blockIdx.x*16;
  if (tid<16){ ceI[tid]=ec[e0+tid]; nbI[tid]=en[e0+tid]; }
  for (int idx=tid; idx<768; idx+=256){ wq[idx]=Wtq[idx]; wkk[idx]=Wtk[idx]; }
  __syncthreads();
  const unsigned short* Xb=(const unsigned short*)(ws+WS_XB);
  for (int idx=tid; idx<1152; idx+=256){ int r=idx/72, p=idx-r*72;
    *(unsigned int*)(xcb + r*144 + 2*p) = *(const unsigned int*)(Xb + (size_t)ceI[r]*144 + 2*p);
    *(unsigned int*)(xnb + r*144 + 2*p) = *(const unsigned int*)(Xb + (size_t)nbI[r]*144 + 2*p); }
  if (tid<144){ int r=tid/9,c=tid%9; sphL[r][c]=sph[(size_t)(e0+r)*9+c]; }
  __syncthreads();
  const int el=tid>>4, j=tid&15;
  float xq[9], xk[9];
  const int ss[3]={0,1,4}, se[3]={1,4,9};
  #pragma unroll
  for (int l=0;l<3;++l){
    for (int mm2=ss[l]; mm2<se[l]; ++mm2){
      float aq=0.f, ak=0.f;
      #pragma unroll
      for (int i=0;i<16;++i){
        float wql = wq[l*256 + j*16 + i], wkl = wkk[l*256 + j*16 + i];
        aq += wql*b2f(xcb[el*144 + i*9+mm2]);
        ak += wkl*b2f(xnb[el*144 + i*9+mm2]);
      }
      xq[mm2]=aq; xk[mm2]=ak;
    }
  }
  float dq=0.f, dk=0.f;
  #pragma unroll
  for (int d=0; d<9; ++d){ dq += xq[d]*sphL[el][d]; dk += xk[d]*sphL[el][d]; }
  #pragma unroll
  for (int d=0; d<9; ++d){ xq[d] -= dq*sphL[el][d]; xk[d] -= dk*sphL[el][d]; }
  const float isc[3] = {1.f, 0.5773502691896258f, 0.4472135954999579f};
  unsigned short* W48u = (unsigned short*)(ws+WS_W48);
  #pragma unroll
  for (int l=0;l<3;++l){
    float s=0.f;
    for (int mm2=ss[l]; mm2<se[l]; ++mm2) s += xq[mm2]*xk[mm2];
    W48u[(size_t)(e0+el)*TPD + l*16 + j] = f2b(s*isc[l]);
  }
}

// ---- K3: per-edge t-update + spatial + alpha via MFMA, 32 edges/block ----
__global__ __launch_bounds__(256) void k3_edge_t(
  const float* __restrict__ t_in, const int* __restrict__ ec, const int* __restrict__ en,
  const unsigned short* __restrict__ WB,
  const float* __restrict__ gw_b1,const float* __restrict__ gw_b2,
  const float* __restrict__ gt_b1,const float* __restrict__ gt_b2,
  const float* __restrict__ Wrs_b,
  const float* __restrict__ ucp, float* __restrict__ ws, float* __restrict__ outT)
{
  __shared__ __align__(16) unsigned short tin_b[32*136], hid_b[32*136];
  __shared__ int ceI[32], nbI[32];
  const int tid=threadIdx.x, lane=tid&63, w=tid>>6, m=lane&15, quad=lane>>4;
  const int e0=blockIdx.x*32;
  if (tid<32){ ceI[tid]=ec[e0+tid]; nbI[tid]=en[e0+tid]; }
  // stage t_in -> bf16 LDS
  for (int idx=tid; idx<1024; idx+=256){ int r=idx>>5, c4=(idx&31)*4;
    float4 tv = *(const float4*)(t_in+(size_t)(e0+r)*128+c4);
    *(unsigned int*)(tin_b+r*136+c4)   = f2b2(tv.x,tv.y);
    *(unsigned int*)(tin_b+r*136+c4+2) = f2b2(tv.z,tv.w); }
  // gw-input A-fragments (bf16 w48) straight to regs
  const unsigned short* W48u=(const unsigned short*)(ws+WS_W48);
  short8 wfr[2][2];
  #pragma unroll
  for (int rr=0;rr<2;++rr){
    const unsigned short* base = W48u + (size_t)(e0 + rr*16 + m)*TPD;
    wfr[rr][0] = *(const short8*)(base + quad*8);
    if (quad<2) wfr[rr][1] = *(const short8*)(base + 32 + quad*8);
    else { short8 z = {0,0,0,0,0,0,0,0}; wfr[rr][1] = z; }
  }
  __syncthreads();
  const float uc=ucp[0], co=rsqrtf(uc*uc+1.f), ucco=uc*co;
  f32x4 z4 = {0.f,0.f,0.f,0.f};
  // P1: gw hidden (K=48 padded to 64, A from regs) -> hid_b
  { f32x4 acc[2][2]={{z4,z4},{z4,z4}};
    #pragma unroll
    for(int i=0;i<2;++i){
      const unsigned short* wp = WB+WOFF_GW1 + (size_t)(w*2+i)*1024 + (size_t)quad*128 + m*8;
      #pragma unroll
      for(int kb=0;kb<2;++kb){
        short8 bfr = *(const short8*)(wp + (size_t)kb*512);
        acc[i][0]=mfma16(wfr[0][kb],bfr,acc[i][0]);
        acc[i][1]=mfma16(wfr[1][kb],bfr,acc[i][1]);
      }
    }
    #pragma unroll
    for(int i=0;i<2;++i){ int col=(w*2+i)*16+m; float bv=gw_b1[col];
      #pragma unroll
      for(int mt=0;mt<2;++mt)
        #pragma unroll
        for(int r=0;r<4;++r) hid_b[(mt*16+quad*4+r)*136+col]=f2b(silu_f(acc[i][mt][r]+bv)); } }
  __syncthreads();
  // P2: gw out -> accw (regs)
  f32x4 accw[2][2]={{z4,z4},{z4,z4}};
  #pragma unroll
  for(int i=0;i<2;++i) mm_tile2<4>(hid_b,136,WB+WOFF_GW2, w*2+i, m, quad, accw[i]);
  __syncthreads();
  // P3: gt hidden -> hid_b (overwrite, post-barrier)
  { f32x4 acc[2][2]={{z4,z4},{z4,z4}};
    #pragma unroll
    for(int i=0;i<2;++i) mm_tile2<4>(tin_b,136,WB+WOFF_GT1, w*2+i, m, quad, acc[i]);
    #pragma unroll
    for(int i=0;i<2;++i){ int col=(w*2+i)*16+m; float bv=gt_b1[col];
      #pragma unroll
      for(int mt=0;mt<2;++mt)
        #pragma unroll
        for(int r=0;r<4;++r) hid_b[(mt*16+quad*4+r)*136+col]=f2b(silu_f(acc[i][mt][r]+bv)); } }
  __syncthreads();
  // P4: gt out; dt = gw*gt; residual -> t_new (in-place into tin_b)
  { f32x4 acct[2][2]={{z4,z4},{z4,z4}};
    #pragma unroll
    for(int i=0;i<2;++i) mm_tile2<4>(hid_b,136,WB+WOFF_GT2, w*2+i, m, quad, acct[i]);
    #pragma unroll
    for(int i=0;i<2;++i){ int col=(w*2+i)*16+m; float bw=gw_b2[col], bt=gt_b2[col];
      #pragma unroll
      for(int mt=0;mt<2;++mt)
        #pragma unroll
        for(int r=0;r<4;++r){ int row=mt*16+quad*4+r;
          float dt=(accw[i][mt][r]+bw)*(acct[i][mt][r]+bt);
          float tn=co*b2f(tin_b[row*136+col]) + ucco*dt;
          tin_b[row*136+col]=f2b(tn);            // same thread owns this slot
          outT[(size_t)(e0+row)*128+col]=tn; } } }
  __syncthreads();
  unsigned short* spatB = (unsigned short*)(ws+WS_SPATB);
  // P5: spatB = (t_new@Wrs + b)  (bf16; S[nb] multiply in k5's coalesced stage)
  { f32x4 acc[2][2]={{z4,z4},{z4,z4}};
    #pragma unroll
    for(int i=0;i<2;++i) mm_tile2<4>(tin_b,136,WB+WOFF_WRS, w*2+i, m, quad, acc[i]);
    #pragma unroll
    for(int i=0;i<2;++i){ int col=(w*2+i)*16+m; float bv=Wrs_b[col];
      #pragma unroll
      for(int mt=0;mt<2;++mt)
        #pragma unroll
        for(int r=0;r<4;++r){ int row=mt*16+quad*4+r;
          spatB[(size_t)(e0+row)*128+col]=f2b(acc[i][mt][r]+bv); } } }
  // P6a: re = silu(t_new@Wre) -> hid_b (bf16; hid_b free after P4)
  { f32x4 acc[2][2]={{z4,z4},{z4,z4}};
    #pragma unroll
    for(int i=0;i<2;++i) mm_tile2<4>(tin_b,136,WB+WOFF_WRE, w*2+i, m, quad, acc[i]);
    #pragma unroll
    for(int i=0;i<2;++i){ int col=(w*2+i)*16+m;
      #pragma unroll
      for(int mt=0;mt<2;++mt)
        #pragma unroll
        for(int r=0;r<4;++r){ int row=mt*16+quad*4+r;
          hid_b[row*136+col]=f2b(silu_f(acc[i][mt][r])); } } }
  __syncthreads();
  // P6b: alpha — 8 lanes/edge, coalesced 2x16B Q/K row loads per lane
  { const unsigned short* Qb=(const unsigned short*)(ws+WS_QB);
    const unsigned short* Kb=(const unsigned short*)(ws+WS_KB);
    unsigned int* amaxu=(unsigned int*)(ws+WS_AMAX);
    const int edge = tid>>3, sub = tid&7, hh = sub>>1, half = sub&1;
    const int ce = ceI[edge], nb = nbI[edge];
    const int cb = hh*32 + half*16;
    uint4 qa0 = *(const uint4*)(Qb + (size_t)ce*128 + cb);
    uint4 qa1 = *(const uint4*)(Qb + (size_t)ce*128 + cb + 8);
    uint4 ka0 = *(const uint4*)(Kb + (size_t)nb*128 + cb);
    uint4 ka1 = *(const uint4*)(Kb + (size_t)nb*128 + cb + 8);
    const unsigned short* reL = hid_b + edge*136 + cb;
    float p = 0.f;
    #pragma unroll
    for (int j=0;j<4;++j){
      unsigned int q0=((const unsigned int*)&qa0)[j], k0=((const unsigned int*)&ka0)[j];
      unsigned int r0=*(const unsigned int*)(reL + 2*j);
      p += b2f((unsigned short)q0)*b2f((unsigned short)k0)*b2f((unsigned short)r0);
      p += b2f((unsigned short)(q0>>16))*b2f((unsigned short)(k0>>16))*b2f((unsigned short)(r0>>16));
      unsigned int q1=((const unsigned int*)&qa1)[j], k1=((const unsigned int*)&ka1)[j];
      unsigned int r1=*(const unsigned int*)(reL + 8 + 2*j);
      p += b2f((unsigned short)q1)*b2f((unsigned short)k1)*b2f((unsigned short)r1);
      p += b2f((unsigned short)(q1>>16))*b2f((unsigned short)(k1>>16))*b2f((unsigned short)(r1>>16));
    }
    p += __shfl_xor(p,1);
    if (half==0){
      float aval = p * 0.17677669529663687f; // 1/sqrt(32)
      int e=e0+edge;
      ws[WS_ALPHA+(size_t)e*4+hh]=aval;
      atomicMax(&amaxu[(size_t)ce*4+hh], fmap(aval));
    } }
}

// ---- K4: ex = exp(alpha - amax[center]); den += ex ----
__global__ __launch_bounds__(256) void k4_softmax(const int* __restrict__ ec, float* __restrict__ ws){
  int i = blockIdx.x*256 + threadIdx.x;
  if (i >= E_EDGES*4) return;
  int e = i>>2, hh = i&3;
  int c = ec[e];
  float a = ws[WS_ALPHA + i];
  const unsigned int* amaxu = (const unsigned int*)(ws + WS_AMAX);
  float am = funmap(amaxu[(size_t)c*4+hh]);
  float exv = __expf(a - am);
  ws[WS_ALPHA + i] = exv;
  atomicAdd(&ws[WS_DEN + (size_t)c*4 + hh], exv);
}

// ---- K5: per-edge gates + segment sums via MFMA, 32 edges/block ----
// 2 LDS buffers (22.3 KB -> 7 blocks/CU): A/B alternate through the phase
// chain; o_t parked in the dead spatB global region between P2 and P4
// (same-block write->read, L2-hot; __syncthreads provides visibility).
__global__ __launch_bounds__(256) void k5_edge_gate(
  const float* __restrict__ sph,
  const int* __restrict__ ec, const int* __restrict__ en,
  const unsigned short* __restrict__ WB,
  const float* __restrict__ gsp_b1,const float* __restrict__ gsp_b2,
  const float* __restrict__ md_b1,const float* __restrict__ md_b2,
  const float* __restrict__ mt_b1,const float* __restrict__ mt_b2,
  float* __restrict__ ws)
{
  __shared__ __align__(16) unsigned short A[32*136], B[32*136];
  __shared__ float gdL[32*16], gtL[32*16], attnL[32*4];
  __shared__ int ceI[32], nbI[32];
  const int tid=threadIdx.x, lane=tid&63, w=tid>>6, m=lane&15, quad=lane>>4;
  const int e0=blockIdx.x*32;
  if (tid<32){ ceI[tid]=ec[e0+tid]; nbI[tid]=en[e0+tid]; }
  __syncthreads();
  if (tid<128){ int r=tid>>2, hh=tid&3;
    attnL[tid] = ws[WS_ALPHA+(size_t)(e0+r)*4+hh] / ws[WS_DEN+(size_t)ceI[r]*4+hh]; }
  __syncthreads();
  const unsigned short* Vb=(const unsigned short*)(ws+WS_VB);
  const unsigned short* Sb=(const unsigned short*)(ws+WS_SB);
  unsigned short* spatB=(unsigned short*)(ws+WS_SPATB);
  // combined = attn*V[nb] + spat*S[nb] -> A   (all three streams row-coalesced)
  for (int idx=tid; idx<2048; idx+=256){ int r=idx>>6, c2=(idx&63)*2;
    unsigned int va = *(const unsigned int*)(Vb+(size_t)nbI[r]*128+c2);
    unsigned int sa = *(const unsigned int*)(Sb+(size_t)nbI[r]*128+c2);
    unsigned int sp = *(const unsigned int*)(spatB+(size_t)(e0+r)*128+c2);
    float a = attnL[r*4+(c2>>5)];
    float v0 = a*b2f((unsigned short)va) + b2f((unsigned short)sp)*b2f((unsigned short)sa);
    float v1 = a*b2f((unsigned short)(va>>16)) + b2f((unsigned short)(sp>>16))*b2f((unsigned short)(sa>>16));
    *(unsigned int*)(A+r*136+c2) = f2b2(v0,v1); }
  __syncthreads();
  f32x4 z4 = {0.f,0.f,0.f,0.f};
  // P1: gsp hidden A -> B
  { f32x4 acc[2][2]={{z4,z4},{z4,z4}};
    #pragma unroll
    for(int i=0;i<2;++i) mm_tile2<4>(A,136,WB+WOFF_GSP1, w*2+i, m, quad, acc[i]);
    #pragma unroll
    for(int i=0;i<2;++i){ int col=(w*2+i)*16+m; float bv=gsp_b1[col];
      #pragma unroll
      for(int mt=0;mt<2;++mt)
        #pragma unroll
        for(int r=0;r<4;++r) B[(mt*16+quad*4+r)*136+col]=f2b(silu_f(acc[i][mt][r]+bv)); } }
  __syncthreads();
  // P2: gsp out (384 cols): o_s pk atomics; o_d -> A (LDS); o_t -> spatB (global, dead region)
  { f32x4 acc[3][2][2];
    #pragma unroll
    for(int g2=0;g2<3;++g2)
      #pragma unroll
      for(int i=0;i<2;++i){ acc[g2][i][0]=z4; acc[g2][i][1]=z4; }
    #pragma unroll
    for(int g2=0;g2<3;++g2)
      #pragma unroll
      for(int i=0;i<2;++i)
        mm_tile2<4>(B,136,WB+WOFF_GSP2, g2*8+w*2+i, m, quad, acc[g2][i]);
    unsigned short* hsumB=(unsigned short*)(ws+WS_HSUM);
    #pragma unroll
    for(int i=0;i<2;++i){ int col=(w*2+i)*16+m;
      float bS=gsp_b2[col], bD=gsp_b2[128+col], bT=gsp_b2[256+col];
      #pragma unroll
      for(int mt=0;mt<2;++mt)
        #pragma unroll
        for(int r=0;r<4;++r){ int row=mt*16+quad*4+r;
          float vS = acc[0][i][mt][r]+bS;
          float vO = __shfl_xor(vS,1);
          if(!(m&1)){
            atom_pk(hsumB + (size_t)ceI[row]*128 + col, f2b2(vS,vO));
          }
          A[row*136+col]=f2b(acc[1][i][mt][r]+bD);
          spatB[(size_t)(e0+row)*128+col]=f2b(acc[2][i][mt][r]+bT); } } }
  __syncthreads();
  // P3: md hidden A -> B
  { f32x4 acc[2][2]={{z4,z4},{z4,z4}};
    #pragma unroll
    for(int i=0;i<2;++i) mm_tile2<4>(A,136,WB+WOFF_MD1, w*2+i, m, quad, acc[i]);
    #pragma unroll
    for(int i=0;i<2;++i){ int col=(w*2+i)*16+m; float bv=md_b1[col];
      #pragma unroll
      for(int mt=0;mt<2;++mt)
        #pragma unroll
        for(int r=0;r<4;++r) B[(mt*16+quad*4+r)*136+col]=f2b(silu_f(acc[i][mt][r]+bv)); } }
  __syncthreads();
  // P4: mt hidden: o_t (global spatB rows, stride 128) -> A
  { f32x4 acc[2][2]={{z4,z4},{z4,z4}};
    const unsigned short* otG = spatB + (size_t)e0*128;
    #pragma unroll
    for(int i=0;i<2;++i) mm_tile2<4>(otG,128,WB+WOFF_MT1, w*2+i, m, quad, acc[i]);
    #pragma unroll
    for(int i=0;i<2;++i){ int col=(w*2+i)*16+m; float bv=mt_b1[col];
      #pragma unroll
      for(int mt=0;mt<2;++mt)
        #pragma unroll
        for(int r=0;r<4;++r) A[(mt*16+quad*4+r)*136+col]=f2b(silu_f(acc[i][mt][r]+bv)); } }
  __syncthreads();
  // P5: gd (waves 0-1 from B), gtt (waves 2-3 from A), N=16
  { if (w<2){
      f32x4 a=z4; mm_tile1<4>(B,136,WB+WOFF_MD2, w, m, quad, a);
      #pragma unroll
      for(int r=0;r<4;++r) gdL[(w*16+quad*4+r)*16+m]=a[r]+md_b2[m];
    } else {
      f32x4 a=z4; mm_tile1<4>(A,136,WB+WOFF_MT2, w-2, m, quad, a);
      #pragma unroll
      for(int r=0;r<4;++r) gtL[((w-2)*16+quad*4+r)*16+m]=a[r]+mt_b2[m];
    } }
  __syncthreads();
  // P6: dXij packed-bf16 atomics (X from bf16 table)
  unsigned short* ndxB=(unsigned short*)(ws+WS_NDX);
  const unsigned short* Xb=(const unsigned short*)(ws+WS_XB);
  for (int idx=tid; idx<2304; idx+=256){
    int r=idx/72, p=idx-r*72; int c0=2*p, c1=c0+1;
    int mm0=c0/9, d0=c0-mm0*9;
    int mm1=c1/9, d1=c1-mm1*9;
    const float* sphE = sph + (size_t)(e0+r)*9;
    unsigned int xa = *(const unsigned int*)(Xb + (size_t)nbI[r]*144 + c0);
    float x0=b2f((unsigned short)xa), x1=b2f((unsigned short)(xa>>16));
    float v0 = gdL[r*16+mm0]*sphE[d0] + gtL[r*16+mm0]*x0;
    float v1 = gdL[r*16+mm1]*sphE[d1] + gtL[r*16+mm1]*x1;
    atom_pk(ndxB + (size_t)ceI[r]*144 + c0, f2b2(v0,v1));
  }
}

// ---- K6: node finalize (hsum/ndx bf16 accumulators) ----
__global__ __launch_bounds__(128) void k6_node(
  const float* __restrict__ h, const float* __restrict__ Xin,
  const float* __restrict__ ln_g,const float* __restrict__ ln_b,
  const float* __restrict__ Wvu,
  const float* __restrict__ gm_W1,const float* __restrict__ gm_b1,
  const float* __restrict__ gm_W2,const float* __restrict__ gm_b2,
  const float* __restrict__ ucp, const float* __restrict__ ws,
  float* __restrict__ outH, float* __restrict__ outX)
{
  __shared__ float cat[4][144], dxb[4][144], xnw[4][144], xp[4][144], hid[4][LAT];
  __shared__ float red[4][2][2], rinv[4][3], gX[4][16], wvu[256];
  const int t=threadIdx.x, n0=blockIdx.x*4;
  const unsigned short* hsumB=(const unsigned short*)(ws+WS_HSUM);
  const unsigned short* ndxB =(const unsigned short*)(ws+WS_NDX);
  const float uc=ucp[0], co=rsqrtf(uc*uc+1.f), ucco=uc*co;
  for (int idx=t; idx<256; idx+=128) wvu[idx]=Wvu[idx];
  for (int idx=t; idx<576; idx+=128){ int r=idx/144,c=idx%144; dxb[r][c]=b2f(ndxB[(size_t)(n0+r)*144+c]); }
  float xv_[4];
  #pragma unroll
  for (int r=0;r<4;++r){
    float x=b2f(hsumB[(size_t)(n0+r)*LAT+t]); xv_[r]=x;
    float s=x, ss=x*x;
    for (int off=32; off; off>>=1){ s+=__shfl_down(s,off,64); ss+=__shfl_down(ss,off,64); }
    if ((t&63)==0){ red[r][t>>6][0]=s; red[r][t>>6][1]=ss; }
  }
  __syncthreads();
  #pragma unroll
  for (int r=0;r<4;++r){
    float s=red[r][0][0]+red[r][1][0], ss=red[r][0][1]+red[r][1][1];
    float mu=s*(1.f/128.f), var=ss*(1.f/128.f)-mu*mu;
    float dh=(xv_[r]-mu)*rsqrtf(var+1e-5f)*ln_g[t]+ln_b[t];
    cat[r][t]=co*h[(size_t)(n0+r)*LAT+t]+ucco*dh;
  }
  if (t<12){
    int r=t/3, l=t-r*3;
    int s0 = (l==0)?0:((l==1)?1:4);
    int s1 = (l==0)?1:((l==1)?4:9);
    float sum=0.f;
    for (int mm2=0;mm2<16;++mm2)
      for (int d=s0;d<s1;++d){ float v=dxb[r][mm2*9+d]; sum+=v*v; }
    rinv[r][l]=rsqrtf(sum*(1.f/16.f)+1e-8f);
  }
  __syncthreads();
  for (int idx=t; idx<144; idx+=128){
    int d=idx%9; int l=(d==0)?0:((d<4)?1:2);
    #pragma unroll
    for (int r=0;r<4;++r)
      xnw[r][idx]=co*Xin[(size_t)(n0+r)*144+idx]+ucco*dxb[r][idx]*rinv[r][l];
  }
  __syncthreads();
  for (int idx=t; idx<144; idx+=128){
    int j=idx/9, i=idx-j*9;
    #pragma unroll
    for (int r=0;r<4;++r){
      float a=0.f;
      #pragma unroll
      for (int mm2=0;mm2<16;++mm2) a+=xnw[r][mm2*9+i]*wvu[mm2*16+j];
      xp[r][idx]=a;
    }
  }
  __syncthreads();
  if (t<64){ int r=t>>4, j=t&15; float s=1e-12f;
    #pragma unroll
    for (int i=0;i<9;++i){ float v=xp[r][j*9+i]; s+=v*v; }
    cat[r][128+j]=sqrtf(s); }
  __syncthreads();
  { float acc[4]; float b=gm_b1[t];
    #pragma unroll
    for(int r=0;r<4;++r)acc[r]=b;
    mm_acc<4,144,144>(&cat[0][0],gm_W1,LAT,t,acc);
    #pragma unroll
    for(int r=0;r<4;++r) hid[r][t]=silu_f(acc[r]); }
  __syncthreads();
  { float acc[4]; float b=gm_b2[t];
    #pragma unroll
    for(int r=0;r<4;++r)acc[r]=b;
    mm_acc<4,LAT,LAT>(&hid[0][0],gm_W2,144,t,acc);
    #pragma unroll
    for(int r=0;r<4;++r) outH[(size_t)(n0+r)*LAT+t]=cat[r][t]+acc[r]; }
  if (t<16){ float acc[4]; float b=gm_b2[128+t];
    #pragma unroll
    for(int r=0;r<4;++r)acc[r]=b;
    for (int k=0;k<LAT;++k){ float wk=gm_W2[(size_t)k*144+128+t];
      #pragma unroll
      for(int r=0;r<4;++r) acc[r]+=hid[r][k]*wk; }
    #pragma unroll
    for(int r=0;r<4;++r) gX[r][t]=acc[r]; }
  __syncthreads();
  for (int idx=t; idx<144; idx+=128){
    int j=idx/9;
    #pragma unroll
    for (int r=0;r<4;++r)
      outX[(size_t)(n0+r)*144+idx]=xnw[r][idx]+gX[r][j]*xp[r][idx];
  }
}

extern "C" void kernel_launch(void* const* d_in, const int* in_sizes, int n_in,
                              void* d_out, int out_size, void* d_ws, size_t ws_size,
                              hipStream_t stream)
{
  const float* h      = (const float*)d_in[0];
  const float* X      = (const float*)d_in[1];
  const float* t_ij   = (const float*)d_in[2];
  const float* sph    = (const float*)d_in[3];
  const float* ucp    = (const float*)d_in[4];
  const float* Wtq    = (const float*)d_in[5];
  const float* Wtk    = (const float*)d_in[6];
  const float* Wrs_W  = (const float*)d_in[7];
  const float* Wrs_b  = (const float*)d_in[8];
  const float* Wq_W   = (const float*)d_in[9];
  const float* Wq_b   = (const float*)d_in[10];
  const float* Wk_W   = (const float*)d_in[11];
  const float* Wk_b   = (const float*)d_in[12];
  const float* Wre_W  = (const float*)d_in[13];
  const float* ln_g   = (const float*)d_in[14];
  const float* ln_b   = (const float*)d_in[15];
  const float* Wvu    = (const float*)d_in[16];
  const float* gs_W1=(const float*)d_in[17], *gs_b1=(const float*)d_in[18],
             *gs_W2=(const float*)d_in[19], *gs_b2=(const float*)d_in[20];
  const float* gv_W1=(const float*)d_in[21], *gv_b1=(const float*)d_in[22],
             *gv_W2=(const float*)d_in[23], *gv_b2=(const float*)d_in[24];
  const float* gw_W1=(const float*)d_in[25], *gw_b1=(const float*)d_in[26],
             *gw_W2=(const float*)d_in[27], *gw_b2=(const float*)d_in[28];
  const float* gt_W1=(const float*)d_in[29], *gt_b1=(const float*)d_in[30],
             *gt_W2=(const float*)d_in[31], *gt_b2=(const float*)d_in[32];
  const float* gsp_W1=(const float*)d_in[33], *gsp_b1=(const float*)d_in[34],
             *gsp_W2=(const float*)d_in[35], *gsp_b2=(const float*)d_in[36];
  const float* md_W1=(const float*)d_in[37], *md_b1=(const float*)d_in[38],
             *md_W2=(const float*)d_in[39], *md_b2=(const float*)d_in[40];
  const float* mt_W1=(const float*)d_in[41], *mt_b1=(const float*)d_in[42],
             *mt_W2=(const float*)d_in[43], *mt_b2=(const float*)d_in[44];
  const float* gm_W1=(const float*)d_in[45], *gm_b1=(const float*)d_in[46],
             *gm_W2=(const float*)d_in[47], *gm_b2=(const float*)d_in[48];
  const int* ec = (const int*)d_in[49];
  const int* en = (const int*)d_in[50];
  (void)in_sizes; (void)n_in; (void)out_size; (void)ws_size;

  float* ws   = (float*)d_ws;
  unsigned short* WB = (unsigned short*)(ws + WS_WB);
  float* outH = (float*)d_out;
  float* outX = outH + (size_t)N_NODES*LAT;
  float* outT = outX + (size_t)N_NODES*MUL*DD;

  k_prep<<<dim3(PREP_ZB + PREP_PB + PREP_XB), dim3(256), 0, stream>>>(
      X, Wq_W,Wk_W, gv_W1,gv_W2, gs_W1,gs_W2, gw_W1,gw_W2, gt_W1,gt_W2,
      Wrs_W,Wre_W, gsp_W1,gsp_W2, md_W1,md_W2, mt_W1,mt_W2, ws);
  k1_node<<<dim3(N_NODES/32), dim3(256), 0, stream>>>(h, WB, Wq_b, Wk_b,
      gv_b1,gv_b2, gs_b1,gs_b2, ws);
  k2_edge_w<<<dim3(E_EDGES/16), dim3(256), 0, stream>>>(sph, Wtq, Wtk, ec, en, ws);
  k3_edge_t<<<dim3(E_EDGES/32), dim3(256), 0, stream>>>(t_ij, ec, en, WB,
      gw_b1,gw_b2, gt_b1,gt_b2, Wrs_b, ucp, ws, outT);
  k4_softmax<<<dim3((E_EDGES*4)/256), dim3(256), 0, stream>>>(ec, ws);
  k5_edge_gate<<<dim3(E_EDGES/32), dim3(256), 0, stream>>>(sph, ec, en, WB,
      gsp_b1,gsp_b2, md_b1,md_b2, mt_b1,mt_b2, ws);
  k6_node<<<dim3(N_NODES/4), dim3(128), 0, stream>>>(h, X, ln_g, ln_b, Wvu,
      gm_W1,gm_b1,gm_W2,gm_b2, ucp, ws, outH, outX);
}

// Round 10
// 742.257 us; speedup vs baseline: 1.0030x; 1.0030x over previous
//
#include <hip/hip_runtime.h>
#include <math.h>

#define N_NODES 20000
#define E_EDGES 160000
#define LAT 128
#define MUL 16
#define DD 9
#define TPD 48

// ---- workspace layout (float offsets) ----
#define WS_QB     ((size_t)0)
#define WS_KB     (WS_QB + (size_t)N_NODES*LAT/2)
#define WS_VB     (WS_KB + (size_t)N_NODES*LAT/2)
#define WS_SB     (WS_VB + (size_t)N_NODES*LAT/2)
#define WS_W48    (WS_SB + (size_t)N_NODES*LAT/2)         // bf16: E*48 ushorts
#define WS_SPATB  (WS_W48 + (size_t)E_EDGES*TPD)          // bf16: E*128 ushorts
#define WS_ALPHA  (WS_SPATB + (size_t)E_EDGES*LAT/2)
#define WS_ZERO   (WS_ALPHA + (size_t)E_EDGES*4)
#define WS_AMAX   WS_ZERO
#define WS_DEN    (WS_AMAX + (size_t)N_NODES*4)
#define WS_HSUM   (WS_DEN + (size_t)N_NODES*4)            // bf16: N*128 ushorts
#define WS_NDX    (WS_HSUM + (size_t)N_NODES*LAT/2)       // bf16: N*144 ushorts
#define WS_END    (WS_NDX + (size_t)N_NODES*72)
#define ZERO_CNT  (WS_END - WS_ZERO)
#define WS_WB     WS_END                                   // ushort (bf16) packed weights
#define WS_XB     (WS_WB + (size_t)145408)                 // bf16 X table: N*144 ushorts

// packed weight offsets (ushort elements)
#define WOFF_WQ   0
#define WOFF_WK   16384
#define WOFF_GV1  32768
#define WOFF_GV2  49152
#define WOFF_GS1  65536
#define WOFF_GS2  81920
#define WOFF_GW1  98304
#define WOFF_GW2  106496
#define WOFF_GT1  122880
#define WOFF_GT2  139264
#define WOFF_WRS  155648
#define WOFF_WRE  172032
#define WOFF_GSP1 188416
#define WOFF_GSP2 204800
#define WOFF_MD1  253952
#define WOFF_MD2  270336
#define WOFF_MT1  272384
#define WOFF_MT2  288768
#define WB_TOTAL  290816

// k_prep block ranges
#define PREP_ZB   11250
#define PREP_PB   1136
#define PREP_XB   5625

#define DEVI __device__ __forceinline__

typedef short short8 __attribute__((ext_vector_type(8)));
typedef float f32x4 __attribute__((ext_vector_type(4)));

DEVI float silu_f(float x){ return x / (1.f + __expf(-x)); }
DEVI unsigned int fmap(float x){ unsigned int b=__float_as_uint(x); return (b&0x80000000u)? ~b : (b|0x80000000u); }
DEVI float funmap(unsigned int u){ return (u&0x80000000u)? __uint_as_float(u&0x7fffffffu) : __uint_as_float(~u); }

// branchless RNE f32->bf16 (proven fastest; hip_bf16 header versions carry NaN-select bloat)
DEVI unsigned short f2b(float f){ unsigned int u=__float_as_uint(f); return (unsigned short)((u + 0x7fffu + ((u>>16)&1u))>>16); }
DEVI unsigned int f2b2(float lo, float hi){ return ((unsigned int)f2b(hi)<<16) | (unsigned int)f2b(lo); }
DEVI float b2f(unsigned short u){ return __uint_as_float(((unsigned int)u)<<16); }

// packed bf16x2 fire-and-forget atomic add (gfx950)
DEVI void atom_pk(unsigned short* p, unsigned int pk){
  asm volatile("global_atomic_pk_add_bf16 %0, %1, off" :: "v"(p), "v"(pk) : "memory");
}

DEVI f32x4 mfma16(short8 a, short8 b, f32x4 c){
  return __builtin_amdgcn_mfma_f32_16x16x32_bf16(a,b,c,0,0,0);
}

template<int KB>
DEVI void mm_tile2(const unsigned short* act, int strideUS, const unsigned short* Wp,
                   int ntile, int m, int quad, f32x4* acc){
  const unsigned short* wp = Wp + (size_t)ntile*KB*512 + (size_t)quad*128 + m*8;
  const unsigned short* a0 = act + m*strideUS + quad*8;
  const unsigned short* a1 = a0 + 16*strideUS;
  #pragma unroll
  for (int kb=0;kb<KB;++kb){
    short8 bfr = *(const short8*)(wp + (size_t)kb*512);
    short8 af0 = *(const short8*)(a0 + kb*32);
    short8 af1 = *(const short8*)(a1 + kb*32);
    acc[0]=mfma16(af0,bfr,acc[0]);
    acc[1]=mfma16(af1,bfr,acc[1]);
  }
}

// single m-tile (16-row activation), column tile `ntile`
template<int KB>
DEVI void mm_tile_m1(const unsigned short* act, int strideUS, const unsigned short* Wp,
                     int ntile, int m, int quad, f32x4& acc){
  const unsigned short* wp = Wp + (size_t)ntile*KB*512 + (size_t)quad*128 + m*8;
  const unsigned short* a0 = act + m*strideUS + quad*8;
  #pragma unroll
  for (int kb=0;kb<KB;++kb){
    short8 bfr = *(const short8*)(wp + (size_t)kb*512);
    short8 af0 = *(const short8*)(a0 + kb*32);
    acc=mfma16(af0,bfr,acc);
  }
}

// single m-tile, ntile 0 (for N=16 outputs)
template<int KB>
DEVI void mm_tile1(const unsigned short* act, int strideUS, const unsigned short* Wp,
                   int mtbase, int m, int quad, f32x4& acc){
  const unsigned short* wp = Wp + (size_t)quad*128 + m*8;
  const unsigned short* a0 = act + (mtbase*16+m)*strideUS + quad*8;
  #pragma unroll
  for (int kb=0;kb<KB;++kb){
    short8 bfr = *(const short8*)(wp + (size_t)kb*512);
    short8 af  = *(const short8*)(a0 + kb*32);
    acc=mfma16(af,bfr,acc);
  }
}

template<int R, int KD, int LDSTRIDE>
DEVI void mm_acc(const float* src, const float* __restrict__ W, int wstride, int t, float* acc){
  #pragma unroll 2
  for (int k=0;k<KD;k+=4){
    float4 xv[R];
    #pragma unroll
    for (int r=0;r<R;++r) xv[r] = *(const float4*)(src + r*LDSTRIDE + k);
    #pragma unroll
    for (int kk=0;kk<4;++kk){
      float wk = W[(size_t)(k+kk)*wstride + t];
      #pragma unroll
      for (int r=0;r<R;++r) acc[r] += ((const float*)&xv[r])[kk]*wk;
    }
  }
}

// ---- K_prep: fused {zero accumulators | pack weights bf16 | X -> bf16 table} ----
__global__ __launch_bounds__(256) void k_prep(
  const float* __restrict__ X,
  const float* __restrict__ Wq,const float* __restrict__ Wk,
  const float* __restrict__ gv1,const float* __restrict__ gv2,
  const float* __restrict__ gs1,const float* __restrict__ gs2,
  const float* __restrict__ gw1,const float* __restrict__ gw2,
  const float* __restrict__ gt1,const float* __restrict__ gt2,
  const float* __restrict__ Wrs,const float* __restrict__ Wre,
  const float* __restrict__ gsp1,const float* __restrict__ gsp2,
  const float* __restrict__ md1,const float* __restrict__ md2,
  const float* __restrict__ mt1,const float* __restrict__ mt2,
  float* __restrict__ ws)
{
  const int b = blockIdx.x, tid = threadIdx.x;
  if (b < PREP_ZB){
    size_t i = (size_t)b*256 + tid;
    if (i < ZERO_CNT) ws[WS_ZERO + i] = 0.f;
    return;
  }
  if (b < PREP_ZB + PREP_PB){
    int i = (b - PREP_ZB)*256 + tid;
    if (i >= WB_TOTAL) return;
    unsigned short* dst = (unsigned short*)(ws + WS_WB);
    const int off[19] = {0,16384,32768,49152,65536,81920,98304,106496,122880,139264,
                         155648,172032,188416,204800,253952,270336,272384,288768,290816};
    int mi=0;
    while (i >= off[mi+1]) ++mi;
    int li = i - off[mi];
    int N = (mi==13)?384:((mi==15||mi==17)?16:128);
    int Ksrc = (mi==6)?48:128;
    int KB = (mi==6)?2:4;
    int j = li&7; int t = li>>3;
    int n_in = t&15; t>>=4;
    int quad = t&3; t>>=2;
    int k_block = t % KB; int n_tile = t / KB;
    int k = k_block*32 + quad*8 + j;
    int n = n_tile*16 + n_in;
    const float* src;
    switch(mi){
      case 0: src=Wq; break;  case 1: src=Wk; break;
      case 2: src=gv1; break; case 3: src=gv2; break;
      case 4: src=gs1; break; case 5: src=gs2; break;
      case 6: src=gw1; break; case 7: src=gw2; break;
      case 8: src=gt1; break; case 9: src=gt2; break;
      case 10: src=Wrs; break; case 11: src=Wre; break;
      case 12: src=gsp1; break; case 13: src=gsp2; break;
      case 14: src=md1; break; case 15: src=md2; break;
      default: src=(mi==16)?mt1:mt2; break;
    }
    float v = (k < Ksrc) ? src[(size_t)k*N + n] : 0.f;
    dst[i] = f2b(v);
    return;
  }
  {
    size_t idx = (size_t)(b - PREP_ZB - PREP_PB)*256 + tid;
    if (idx < (size_t)N_NODES*72){
      float2 v = *(const float2*)(X + idx*2);
      ((unsigned int*)(ws + WS_XB))[idx] = f2b2(v.x, v.y);
    }
    return;
  }
}

// ---- K1: per-node Q,K,V(gv),S(gs) via MFMA, 16 nodes/block (1250 blocks) ----
// Halved tile vs 32-node version: per-block MFMA chain halves, 2x machine fill
// (625 blocks = 2.4/CU was the worst-filled kernel; latency set by one block's
// serial 6-phase chain, not throughput).
__global__ __launch_bounds__(256) void k1_node(const float* __restrict__ h,
  const unsigned short* __restrict__ WB,
  const float* __restrict__ Wq_b,const float* __restrict__ Wk_b,
  const float* __restrict__ gv_b1,const float* __restrict__ gv_b2,
  const float* __restrict__ gs_b1,const float* __restrict__ gs_b2,
  float* __restrict__ ws)
{
  __shared__ __align__(16) unsigned short B0[16*136], B1[16*136];
  const int tid=threadIdx.x, lane=tid&63, w=tid>>6, m=lane&15, quad=lane>>4;
  const int n0=blockIdx.x*16;
  for (int idx=tid; idx<512; idx+=256){ int r=idx>>5, c4=(idx&31)*4;
    float4 hv = *(const float4*)(h+(size_t)(n0+r)*128+c4);
    *(unsigned int*)(B0+r*136+c4)   = f2b2(hv.x,hv.y);
    *(unsigned int*)(B0+r*136+c4+2) = f2b2(hv.z,hv.w); }
  __syncthreads();
  unsigned short* Qb=(unsigned short*)(ws+WS_QB);
  unsigned short* Kb=(unsigned short*)(ws+WS_KB);
  unsigned short* Vb=(unsigned short*)(ws+WS_VB);
  unsigned short* Sb=(unsigned short*)(ws+WS_SB);
  f32x4 z4 = {0.f,0.f,0.f,0.f};
  // Q
  { f32x4 acc[2]={z4,z4};
    #pragma unroll
    for(int i=0;i<2;++i) mm_tile_m1<4>(B0,136,WB+WOFF_WQ, w*2+i, m, quad, acc[i]);
    #pragma unroll
    for(int i=0;i<2;++i){ int col=(w*2+i)*16+m; float bv=Wq_b[col];
      #pragma unroll
      for(int r=0;r<4;++r){ int row=quad*4+r;
        Qb[(size_t)(n0+row)*128+col]=f2b(acc[i][r]+bv); } } }
  // K
  { f32x4 acc[2]={z4,z4};
    #pragma unroll
    for(int i=0;i<2;++i) mm_tile_m1<4>(B0,136,WB+WOFF_WK, w*2+i, m, quad, acc[i]);
    #pragma unroll
    for(int i=0;i<2;++i){ int col=(w*2+i)*16+m; float bv=Wk_b[col];
      #pragma unroll
      for(int r=0;r<4;++r){ int row=quad*4+r;
        Kb[(size_t)(n0+row)*128+col]=f2b(acc[i][r]+bv); } } }
  // gv hidden
  { f32x4 acc[2]={z4,z4};
    #pragma unroll
    for(int i=0;i<2;++i) mm_tile_m1<4>(B0,136,WB+WOFF_GV1, w*2+i, m, quad, acc[i]);
    #pragma unroll
    for(int i=0;i<2;++i){ int col=(w*2+i)*16+m; float bv=gv_b1[col];
      #pragma unroll
      for(int r=0;r<4;++r) B1[(quad*4+r)*136+col]=f2b(silu_f(acc[i][r]+bv)); } }
  __syncthreads();
  // V out
  { f32x4 acc[2]={z4,z4};
    #pragma unroll
    for(int i=0;i<2;++i) mm_tile_m1<4>(B1,136,WB+WOFF_GV2, w*2+i, m, quad, acc[i]);
    #pragma unroll
    for(int i=0;i<2;++i){ int col=(w*2+i)*16+m; float bv=gv_b2[col];
      #pragma unroll
      for(int r=0;r<4;++r){ int row=quad*4+r;
        Vb[(size_t)(n0+row)*128+col]=f2b(acc[i][r]+bv); } } }
  __syncthreads();
  // gs hidden
  { f32x4 acc[2]={z4,z4};
    #pragma unroll
    for(int i=0;i<2;++i) mm_tile_m1<4>(B0,136,WB+WOFF_GS1, w*2+i, m, quad, acc[i]);
    #pragma unroll
    for(int i=0;i<2;++i){ int col=(w*2+i)*16+m; float bv=gs_b1[col];
      #pragma unroll
      for(int r=0;r<4;++r) B1[(quad*4+r)*136+col]=f2b(silu_f(acc[i][r]+bv)); } }
  __syncthreads();
  // S out
  { f32x4 acc[2]={z4,z4};
    #pragma unroll
    for(int i=0;i<2;++i) mm_tile_m1<4>(B1,136,WB+WOFF_GS2, w*2+i, m, quad, acc[i]);
    #pragma unroll
    for(int i=0;i<2;++i){ int col=(w*2+i)*16+m; float bv=gs_b2[col];
      #pragma unroll
      for(int r=0;r<4;++r){ int row=quad*4+r;
        Sb[(size_t)(n0+row)*128+col]=f2b(acc[i][r]+bv); } } }
}

// ---- K2: per-edge w (eq_linear + rejection + slice dots) — bf16 X gathers ----
__global__ __launch_bounds__(256) void k2_edge_w(
  const float* __restrict__ sph,
  const float* __restrict__ Wtq, const float* __restrict__ Wtk,
  const int* __restrict__ ec, const int* __restrict__ en, float* __restrict__ ws)
{
  __shared__ unsigned short xcb[16*144], xnb[16*144];
  __shared__ float sphL[16][9];
  __shared__ float wq[768], wkk[768];
  __shared__ int ceI[16], nbI[16];
  const int tid=threadIdx.x, e0=blockIdx.x*16;
  if (tid<16){ ceI[tid]=ec[e0+tid]; nbI[tid]=en[e0+tid]; }
  for (int idx=tid; idx<768; idx+=256){ wq[idx]=Wtq[idx]; wkk[idx]=Wtk[idx]; }
  __syncthreads();
  const unsigned short* Xb=(const unsigned short*)(ws+WS_XB);
  for (int idx=tid; idx<1152; idx+=256){ int r=idx/72, p=idx-r*72;
    *(unsigned int*)(xcb + r*144 + 2*p) = *(const unsigned int*)(Xb + (size_t)ceI[r]*144 + 2*p);
    *(unsigned int*)(xnb + r*144 + 2*p) = *(const unsigned int*)(Xb + (size_t)nbI[r]*144 + 2*p); }
  if (tid<144){ int r=tid/9,c=tid%9; sphL[r][c]=sph[(size_t)(e0+r)*9+c]; }
  __syncthreads();
  const int el=tid>>4, j=tid&15;
  float xq[9], xk[9];
  const int ss[3]={0,1,4}, se[3]={1,4,9};
  #pragma unroll
  for (int l=0;l<3;++l){
    for (int mm2=ss[l]; mm2<se[l]; ++mm2){
      float aq=0.f, ak=0.f;
      #pragma unroll
      for (int i=0;i<16;++i){
        float wql = wq[l*256 + j*16 + i], wkl = wkk[l*256 + j*16 + i];
        aq += wql*b2f(xcb[el*144 + i*9+mm2]);
        ak += wkl*b2f(xnb[el*144 + i*9+mm2]);
      }
      xq[mm2]=aq; xk[mm2]=ak;
    }
  }
  float dq=0.f, dk=0.f;
  #pragma unroll
  for (int d=0; d<9; ++d){ dq += xq[d]*sphL[el][d]; dk += xk[d]*sphL[el][d]; }
  #pragma unroll
  for (int d=0; d<9; ++d){ xq[d] -= dq*sphL[el][d]; xk[d] -= dk*sphL[el][d]; }
  const float isc[3] = {1.f, 0.5773502691896258f, 0.4472135954999579f};
  unsigned short* W48u = (unsigned short*)(ws+WS_W48);
  #pragma unroll
  for (int l=0;l<3;++l){
    float s=0.f;
    for (int mm2=ss[l]; mm2<se[l]; ++mm2) s += xq[mm2]*xk[mm2];
    W48u[(size_t)(e0+el)*TPD + l*16 + j] = f2b(s*isc[l]);
  }
}

// ---- K3: per-edge t-update + spatial + alpha via MFMA, 32 edges/block ----
__global__ __launch_bounds__(256) void k3_edge_t(
  const float* __restrict__ t_in, const int* __restrict__ ec, const int* __restrict__ en,
  const unsigned short* __restrict__ WB,
  const float* __restrict__ gw_b1,const float* __restrict__ gw_b2,
  const float* __restrict__ gt_b1,const float* __restrict__ gt_b2,
  const float* __restrict__ Wrs_b,
  const float* __restrict__ ucp, float* __restrict__ ws, float* __restrict__ outT)
{
  __shared__ __align__(16) unsigned short tin_b[32*136], hid_b[32*136];
  __shared__ int ceI[32], nbI[32];
  const int tid=threadIdx.x, lane=tid&63, w=tid>>6, m=lane&15, quad=lane>>4;
  const int e0=blockIdx.x*32;
  if (tid<32){ ceI[tid]=ec[e0+tid]; nbI[tid]=en[e0+tid]; }
  // stage t_in -> bf16 LDS
  for (int idx=tid; idx<1024; idx+=256){ int r=idx>>5, c4=(idx&31)*4;
    float4 tv = *(const float4*)(t_in+(size_t)(e0+r)*128+c4);
    *(unsigned int*)(tin_b+r*136+c4)   = f2b2(tv.x,tv.y);
    *(unsigned int*)(tin_b+r*136+c4+2) = f2b2(tv.z,tv.w); }
  // gw-input A-fragments (bf16 w48) straight to regs
  const unsigned short* W48u=(const unsigned short*)(ws+WS_W48);
  short8 wfr[2][2];
  #pragma unroll
  for (int rr=0;rr<2;++rr){
    const unsigned short* base = W48u + (size_t)(e0 + rr*16 + m)*TPD;
    wfr[rr][0] = *(const short8*)(base + quad*8);
    if (quad<2) wfr[rr][1] = *(const short8*)(base + 32 + quad*8);
    else { short8 z = {0,0,0,0,0,0,0,0}; wfr[rr][1] = z; }
  }
  __syncthreads();
  const float uc=ucp[0], co=rsqrtf(uc*uc+1.f), ucco=uc*co;
  f32x4 z4 = {0.f,0.f,0.f,0.f};
  // P1: gw hidden (K=48 padded to 64, A from regs) -> hid_b
  { f32x4 acc[2][2]={{z4,z4},{z4,z4}};
    #pragma unroll
    for(int i=0;i<2;++i){
      const unsigned short* wp = WB+WOFF_GW1 + (size_t)(w*2+i)*1024 + (size_t)quad*128 + m*8;
      #pragma unroll
      for(int kb=0;kb<2;++kb){
        short8 bfr = *(const short8*)(wp + (size_t)kb*512);
        acc[i][0]=mfma16(wfr[0][kb],bfr,acc[i][0]);
        acc[i][1]=mfma16(wfr[1][kb],bfr,acc[i][1]);
      }
    }
    #pragma unroll
    for(int i=0;i<2;++i){ int col=(w*2+i)*16+m; float bv=gw_b1[col];
      #pragma unroll
      for(int mt=0;mt<2;++mt)
        #pragma unroll
        for(int r=0;r<4;++r) hid_b[(mt*16+quad*4+r)*136+col]=f2b(silu_f(acc[i][mt][r]+bv)); } }
  __syncthreads();
  // P2: gw out -> accw (regs)
  f32x4 accw[2][2]={{z4,z4},{z4,z4}};
  #pragma unroll
  for(int i=0;i<2;++i) mm_tile2<4>(hid_b,136,WB+WOFF_GW2, w*2+i, m, quad, accw[i]);
  __syncthreads();
  // P3: gt hidden -> hid_b (overwrite, post-barrier)
  { f32x4 acc[2][2]={{z4,z4},{z4,z4}};
    #pragma unroll
    for(int i=0;i<2;++i) mm_tile2<4>(tin_b,136,WB+WOFF_GT1, w*2+i, m, quad, acc[i]);
    #pragma unroll
    for(int i=0;i<2;++i){ int col=(w*2+i)*16+m; float bv=gt_b1[col];
      #pragma unroll
      for(int mt=0;mt<2;++mt)
        #pragma unroll
        for(int r=0;r<4;++r) hid_b[(mt*16+quad*4+r)*136+col]=f2b(silu_f(acc[i][mt][r]+bv)); } }
  __syncthreads();
  // P4: gt out; dt = gw*gt; residual -> t_new (in-place into tin_b)
  { f32x4 acct[2][2]={{z4,z4},{z4,z4}};
    #pragma unroll
    for(int i=0;i<2;++i) mm_tile2<4>(hid_b,136,WB+WOFF_GT2, w*2+i, m, quad, acct[i]);
    #pragma unroll
    for(int i=0;i<2;++i){ int col=(w*2+i)*16+m; float bw=gw_b2[col], bt=gt_b2[col];
      #pragma unroll
      for(int mt=0;mt<2;++mt)
        #pragma unroll
        for(int r=0;r<4;++r){ int row=mt*16+quad*4+r;
          float dt=(accw[i][mt][r]+bw)*(acct[i][mt][r]+bt);
          float tn=co*b2f(tin_b[row*136+col]) + ucco*dt;
          tin_b[row*136+col]=f2b(tn);            // same thread owns this slot
          outT[(size_t)(e0+row)*128+col]=tn; } } }
  __syncthreads();
  unsigned short* spatB = (unsigned short*)(ws+WS_SPATB);
  // P5: spatB = (t_new@Wrs + b)  (bf16; S[nb] multiply in k5's coalesced stage)
  { f32x4 acc[2][2]={{z4,z4},{z4,z4}};
    #pragma unroll
    for(int i=0;i<2;++i) mm_tile2<4>(tin_b,136,WB+WOFF_WRS, w*2+i, m, quad, acc[i]);
    #pragma unroll
    for(int i=0;i<2;++i){ int col=(w*2+i)*16+m; float bv=Wrs_b[col];
      #pragma unroll
      for(int mt=0;mt<2;++mt)
        #pragma unroll
        for(int r=0;r<4;++r){ int row=mt*16+quad*4+r;
          spatB[(size_t)(e0+row)*128+col]=f2b(acc[i][mt][r]+bv); } } }
  // P6a: re = silu(t_new@Wre) -> hid_b (bf16; hid_b free after P4)
  { f32x4 acc[2][2]={{z4,z4},{z4,z4}};
    #pragma unroll
    for(int i=0;i<2;++i) mm_tile2<4>(tin_b,136,WB+WOFF_WRE, w*2+i, m, quad, acc[i]);
    #pragma unroll
    for(int i=0;i<2;++i){ int col=(w*2+i)*16+m;
      #pragma unroll
      for(int mt=0;mt<2;++mt)
        #pragma unroll
        for(int r=0;r<4;++r){ int row=mt*16+quad*4+r;
          hid_b[row*136+col]=f2b(silu_f(acc[i][mt][r])); } } }
  __syncthreads();
  // P6b: alpha — 8 lanes/edge, coalesced 2x16B Q/K row loads per lane
  { const unsigned short* Qb=(const unsigned short*)(ws+WS_QB);
    const unsigned short* Kb=(const unsigned short*)(ws+WS_KB);
    unsigned int* amaxu=(unsigned int*)(ws+WS_AMAX);
    const int edge = tid>>3, sub = tid&7, hh = sub>>1, half = sub&1;
    const int ce = ceI[edge], nb = nbI[edge];
    const int cb = hh*32 + half*16;
    uint4 qa0 = *(const uint4*)(Qb + (size_t)ce*128 + cb);
    uint4 qa1 = *(const uint4*)(Qb + (size_t)ce*128 + cb + 8);
    uint4 ka0 = *(const uint4*)(Kb + (size_t)nb*128 + cb);
    uint4 ka1 = *(const uint4*)(Kb + (size_t)nb*128 + cb + 8);
    const unsigned short* reL = hid_b + edge*136 + cb;
    float p = 0.f;
    #pragma unroll
    for (int j=0;j<4;++j){
      unsigned int q0=((const unsigned int*)&qa0)[j], k0=((const unsigned int*)&ka0)[j];
      unsigned int r0=*(const unsigned int*)(reL + 2*j);
      p += b2f((unsigned short)q0)*b2f((unsigned short)k0)*b2f((unsigned short)r0);
      p += b2f((unsigned short)(q0>>16))*b2f((unsigned short)(k0>>16))*b2f((unsigned short)(r0>>16));
      unsigned int q1=((const unsigned int*)&qa1)[j], k1=((const unsigned int*)&ka1)[j];
      unsigned int r1=*(const unsigned int*)(reL + 8 + 2*j);
      p += b2f((unsigned short)q1)*b2f((unsigned short)k1)*b2f((unsigned short)r1);
      p += b2f((unsigned short)(q1>>16))*b2f((unsigned short)(k1>>16))*b2f((unsigned short)(r1>>16));
    }
    p += __shfl_xor(p,1);
    if (half==0){
      float aval = p * 0.17677669529663687f; // 1/sqrt(32)
      int e=e0+edge;
      ws[WS_ALPHA+(size_t)e*4+hh]=aval;
      atomicMax(&amaxu[(size_t)ce*4+hh], fmap(aval));
    } }
}

// ---- K4: ex = exp(alpha - amax[center]); den += ex ----
__global__ __launch_bounds__(256) void k4_softmax(const int* __restrict__ ec, float* __restrict__ ws){
  int i = blockIdx.x*256 + threadIdx.x;
  if (i >= E_EDGES*4) return;
  int e = i>>2, hh = i&3;
  int c = ec[e];
  float a = ws[WS_ALPHA + i];
  const unsigned int* amaxu = (const unsigned int*)(ws + WS_AMAX);
  float am = funmap(amaxu[(size_t)c*4+hh]);
  float exv = __expf(a - am);
  ws[WS_ALPHA + i] = exv;
  atomicAdd(&ws[WS_DEN + (size_t)c*4 + hh], exv);
}

// ---- K5: per-edge gates + segment sums via MFMA, 32 edges/block (3 LDS buffers) ----
// R8 proven configuration: 31 KB LDS, o_t in LDS buffer C. (R9's o_t-to-global
// 2-buffer variant: occupancy stayed pinned ~41% and WRITE grew 40 MB — reverted.)
__global__ __launch_bounds__(256) void k5_edge_gate(
  const float* __restrict__ sph,
  const int* __restrict__ ec, const int* __restrict__ en,
  const unsigned short* __restrict__ WB,
  const float* __restrict__ gsp_b1,const float* __restrict__ gsp_b2,
  const float* __restrict__ md_b1,const float* __restrict__ md_b2,
  const float* __restrict__ mt_b1,const float* __restrict__ mt_b2,
  float* __restrict__ ws)
{
  __shared__ __align__(16) unsigned short A[32*136], B[32*136], C[32*136];
  __shared__ float gdL[32*16], gtL[32*16], attnL[32*4];
  __shared__ int ceI[32], nbI[32];
  const int tid=threadIdx.x, lane=tid&63, w=tid>>6, m=lane&15, quad=lane>>4;
  const int e0=blockIdx.x*32;
  if (tid<32){ ceI[tid]=ec[e0+tid]; nbI[tid]=en[e0+tid]; }
  __syncthreads();
  if (tid<128){ int r=tid>>2, hh=tid&3;
    attnL[tid] = ws[WS_ALPHA+(size_t)(e0+r)*4+hh] / ws[WS_DEN+(size_t)ceI[r]*4+hh]; }
  __syncthreads();
  const unsigned short* Vb=(const unsigned short*)(ws+WS_VB);
  const unsigned short* Sb=(const unsigned short*)(ws+WS_SB);
  const unsigned short* spatB=(const unsigned short*)(ws+WS_SPATB);
  // combined = attn*V[nb] + spat*S[nb] -> A   (all three streams row-coalesced)
  for (int idx=tid; idx<2048; idx+=256){ int r=idx>>6, c2=(idx&63)*2;
    unsigned int va = *(const unsigned int*)(Vb+(size_t)nbI[r]*128+c2);
    unsigned int sa = *(const unsigned int*)(Sb+(size_t)nbI[r]*128+c2);
    unsigned int sp = *(const unsigned int*)(spatB+(size_t)(e0+r)*128+c2);
    float a = attnL[r*4+(c2>>5)];
    float v0 = a*b2f((unsigned short)va) + b2f((unsigned short)sp)*b2f((unsigned short)sa);
    float v1 = a*b2f((unsigned short)(va>>16)) + b2f((unsigned short)(sp>>16))*b2f((unsigned short)(sa>>16));
    *(unsigned int*)(A+r*136+c2) = f2b2(v0,v1); }
  __syncthreads();
  f32x4 z4 = {0.f,0.f,0.f,0.f};
  // P1: gsp hidden A -> B
  { f32x4 acc[2][2]={{z4,z4},{z4,z4}};
    #pragma unroll
    for(int i=0;i<2;++i) mm_tile2<4>(A,136,WB+WOFF_GSP1, w*2+i, m, quad, acc[i]);
    #pragma unroll
    for(int i=0;i<2;++i){ int col=(w*2+i)*16+m; float bv=gsp_b1[col];
      #pragma unroll
      for(int mt=0;mt<2;++mt)
        #pragma unroll
        for(int r=0;r<4;++r) B[(mt*16+quad*4+r)*136+col]=f2b(silu_f(acc[i][mt][r]+bv)); } }
  __syncthreads();
  // P2: gsp out (384 cols): o_s pk atomics; o_d -> A; o_t -> C
  { f32x4 acc[3][2][2];
    #pragma unroll
    for(int g2=0;g2<3;++g2)
      #pragma unroll
      for(int i=0;i<2;++i){ acc[g2][i][0]=z4; acc[g2][i][1]=z4; }
    #pragma unroll
    for(int g2=0;g2<3;++g2)
      #pragma unroll
      for(int i=0;i<2;++i)
        mm_tile2<4>(B,136,WB+WOFF_GSP2, g2*8+w*2+i, m, quad, acc[g2][i]);
    unsigned short* hsumB=(unsigned short*)(ws+WS_HSUM);
    #pragma unroll
    for(int i=0;i<2;++i){ int col=(w*2+i)*16+m;
      float bS=gsp_b2[col], bD=gsp_b2[128+col], bT=gsp_b2[256+col];
      #pragma unroll
      for(int mt=0;mt<2;++mt)
        #pragma unroll
        for(int r=0;r<4;++r){ int row=mt*16+quad*4+r;
          float vS = acc[0][i][mt][r]+bS;
          float vO = __shfl_xor(vS,1);
          if(!(m&1)){
            atom_pk(hsumB + (size_t)ceI[row]*128 + col, f2b2(vS,vO));
          }
          A[row*136+col]=f2b(acc[1][i][mt][r]+bD);
          C[row*136+col]=f2b(acc[2][i][mt][r]+bT); } } }
  __syncthreads();
  // P3: md hidden A -> B
  { f32x4 acc[2][2]={{z4,z4},{z4,z4}};
    #pragma unroll
    for(int i=0;i<2;++i) mm_tile2<4>(A,136,WB+WOFF_MD1, w*2+i, m, quad, acc[i]);
    #pragma unroll
    for(int i=0;i<2;++i){ int col=(w*2+i)*16+m; float bv=md_b1[col];
      #pragma unroll
      for(int mt=0;mt<2;++mt)
        #pragma unroll
        for(int r=0;r<4;++r) B[(mt*16+quad*4+r)*136+col]=f2b(silu_f(acc[i][mt][r]+bv)); } }
  __syncthreads();
  // P4: mt hidden C -> A
  { f32x4 acc[2][2]={{z4,z4},{z4,z4}};
    #pragma unroll
    for(int i=0;i<2;++i) mm_tile2<4>(C,136,WB+WOFF_MT1, w*2+i, m, quad, acc[i]);
    #pragma unroll
    for(int i=0;i<2;++i){ int col=(w*2+i)*16+m; float bv=mt_b1[col];
      #pragma unroll
      for(int mt=0;mt<2;++mt)
        #pragma unroll
        for(int r=0;r<4;++r) A[(mt*16+quad*4+r)*136+col]=f2b(silu_f(acc[i][mt][r]+bv)); } }
  __syncthreads();
  // P5: gd (waves 0-1 from B), gtt (waves 2-3 from A), N=16
  { if (w<2){
      f32x4 a=z4; mm_tile1<4>(B,136,WB+WOFF_MD2, w, m, quad, a);
      #pragma unroll
      for(int r=0;r<4;++r) gdL[(w*16+quad*4+r)*16+m]=a[r]+md_b2[m];
    } else {
      f32x4 a=z4; mm_tile1<4>(A,136,WB+WOFF_MT2, w-2, m, quad, a);
      #pragma unroll
      for(int r=0;r<4;++r) gtL[((w-2)*16+quad*4+r)*16+m]=a[r]+mt_b2[m];
    } }
  __syncthreads();
  // P6: dXij packed-bf16 atomics (X from bf16 table)
  unsigned short* ndxB=(unsigned short*)(ws+WS_NDX);
  const unsigned short* Xb=(const unsigned short*)(ws+WS_XB);
  for (int idx=tid; idx<2304; idx+=256){
    int r=idx/72, p=idx-r*72; int c0=2*p, c1=c0+1;
    int mm0=c0/9, d0=c0-mm0*9;
    int mm1=c1/9, d1=c1-mm1*9;
    const float* sphE = sph + (size_t)(e0+r)*9;
    unsigned int xa = *(const unsigned int*)(Xb + (size_t)nbI[r]*144 + c0);
    float x0=b2f((unsigned short)xa), x1=b2f((unsigned short)(xa>>16));
    float v0 = gdL[r*16+mm0]*sphE[d0] + gtL[r*16+mm0]*x0;
    float v1 = gdL[r*16+mm1]*sphE[d1] + gtL[r*16+mm1]*x1;
    atom_pk(ndxB + (size_t)ceI[r]*144 + c0, f2b2(v0,v1));
  }
}

// ---- K6: node finalize (hsum/ndx bf16 accumulators) ----
__global__ __launch_bounds__(128) void k6_node(
  const float* __restrict__ h, const float* __restrict__ Xin,
  const float* __restrict__ ln_g,const float* __restrict__ ln_b,
  const float* __restrict__ Wvu,
  const float* __restrict__ gm_W1,const float* __restrict__ gm_b1,
  const float* __restrict__ gm_W2,const float* __restrict__ gm_b2,
  const float* __restrict__ ucp, const float* __restrict__ ws,
  float* __restrict__ outH, float* __restrict__ outX)
{
  __shared__ float cat[4][144], dxb[4][144], xnw[4][144], xp[4][144], hid[4][LAT];
  __shared__ float red[4][2][2], rinv[4][3], gX[4][16], wvu[256];
  const int t=threadIdx.x, n0=blockIdx.x*4;
  const unsigned short* hsumB=(const unsigned short*)(ws+WS_HSUM);
  const unsigned short* ndxB =(const unsigned short*)(ws+WS_NDX);
  const float uc=ucp[0], co=rsqrtf(uc*uc+1.f), ucco=uc*co;
  for (int idx=t; idx<256; idx+=128) wvu[idx]=Wvu[idx];
  for (int idx=t; idx<576; idx+=128){ int r=idx/144,c=idx%144; dxb[r][c]=b2f(ndxB[(size_t)(n0+r)*144+c]); }
  float xv_[4];
  #pragma unroll
  for (int r=0;r<4;++r){
    float x=b2f(hsumB[(size_t)(n0+r)*LAT+t]); xv_[r]=x;
    float s=x, ss=x*x;
    for (int off=32; off; off>>=1){ s+=__shfl_down(s,off,64); ss+=__shfl_down(ss,off,64); }
    if ((t&63)==0){ red[r][t>>6][0]=s; red[r][t>>6][1]=ss; }
  }
  __syncthreads();
  #pragma unroll
  for (int r=0;r<4;++r){
    float s=red[r][0][0]+red[r][1][0], ss=red[r][0][1]+red[r][1][1];
    float mu=s*(1.f/128.f), var=ss*(1.f/128.f)-mu*mu;
    float dh=(xv_[r]-mu)*rsqrtf(var+1e-5f)*ln_g[t]+ln_b[t];
    cat[r][t]=co*h[(size_t)(n0+r)*LAT+t]+ucco*dh;
  }
  if (t<12){
    int r=t/3, l=t-r*3;
    int s0 = (l==0)?0:((l==1)?1:4);
    int s1 = (l==0)?1:((l==1)?4:9);
    float sum=0.f;
    for (int mm2=0;mm2<16;++mm2)
      for (int d=s0;d<s1;++d){ float v=dxb[r][mm2*9+d]; sum+=v*v; }
    rinv[r][l]=rsqrtf(sum*(1.f/16.f)+1e-8f);
  }
  __syncthreads();
  for (int idx=t; idx<144; idx+=128){
    int d=idx%9; int l=(d==0)?0:((d<4)?1:2);
    #pragma unroll
    for (int r=0;r<4;++r)
      xnw[r][idx]=co*Xin[(size_t)(n0+r)*144+idx]+ucco*dxb[r][idx]*rinv[r][l];
  }
  __syncthreads();
  for (int idx=t; idx<144; idx+=128){
    int j=idx/9, i=idx-j*9;
    #pragma unroll
    for (int r=0;r<4;++r){
      float a=0.f;
      #pragma unroll
      for (int mm2=0;mm2<16;++mm2) a+=xnw[r][mm2*9+i]*wvu[mm2*16+j];
      xp[r][idx]=a;
    }
  }
  __syncthreads();
  if (t<64){ int r=t>>4, j=t&15; float s=1e-12f;
    #pragma unroll
    for (int i=0;i<9;++i){ float v=xp[r][j*9+i]; s+=v*v; }
    cat[r][128+j]=sqrtf(s); }
  __syncthreads();
  { float acc[4]; float b=gm_b1[t];
    #pragma unroll
    for(int r=0;r<4;++r)acc[r]=b;
    mm_acc<4,144,144>(&cat[0][0],gm_W1,LAT,t,acc);
    #pragma unroll
    for(int r=0;r<4;++r) hid[r][t]=silu_f(acc[r]); }
  __syncthreads();
  { float acc[4]; float b=gm_b2[t];
    #pragma unroll
    for(int r=0;r<4;++r)acc[r]=b;
    mm_acc<4,LAT,LAT>(&hid[0][0],gm_W2,144,t,acc);
    #pragma unroll
    for(int r=0;r<4;++r) outH[(size_t)(n0+r)*LAT+t]=cat[r][t]+acc[r]; }
  if (t<16){ float acc[4]; float b=gm_b2[128+t];
    #pragma unroll
    for(int r=0;r<4;++r)acc[r]=b;
    for (int k=0;k<LAT;++k){ float wk=gm_W2[(size_t)k*144+128+t];
      #pragma unroll
      for(int r=0;r<4;++r) acc[r]+=hid[r][k]*wk; }
    #pragma unroll
    for(int r=0;r<4;++r) gX[r][t]=acc[r]; }
  __syncthreads();
  for (int idx=t; idx<144; idx+=128){
    int j=idx/9;
    #pragma unroll
    for (int r=0;r<4;++r)
      outX[(size_t)(n0+r)*144+idx]=xnw[r][idx]+gX[r][j]*xp[r][idx];
  }
}

extern "C" void kernel_launch(void* const* d_in, const int* in_sizes, int n_in,
                              void* d_out, int out_size, void* d_ws, size_t ws_size,
                              hipStream_t stream)
{
  const float* h      = (const float*)d_in[0];
  const float* X      = (const float*)d_in[1];
  const float* t_ij   = (const float*)d_in[2];
  const float* sph    = (const float*)d_in[3];
  const float* ucp    = (const float*)d_in[4];
  const float* Wtq    = (const float*)d_in[5];
  const float* Wtk    = (const float*)d_in[6];
  const float* Wrs_W  = (const float*)d_in[7];
  const float* Wrs_b  = (const float*)d_in[8];
  const float* Wq_W   = (const float*)d_in[9];
  const float* Wq_b   = (const float*)d_in[10];
  const float* Wk_W   = (const float*)d_in[11];
  const float* Wk_b   = (const float*)d_in[12];
  const float* Wre_W  = (const float*)d_in[13];
  const float* ln_g   = (const float*)d_in[14];
  const float* ln_b   = (const float*)d_in[15];
  const float* Wvu    = (const float*)d_in[16];
  const float* gs_W1=(const float*)d_in[17], *gs_b1=(const float*)d_in[18],
             *gs_W2=(const float*)d_in[19], *gs_b2=(const float*)d_in[20];
  const float* gv_W1=(const float*)d_in[21], *gv_b1=(const float*)d_in[22],
             *gv_W2=(const float*)d_in[23], *gv_b2=(const float*)d_in[24];
  const float* gw_W1=(const float*)d_in[25], *gw_b1=(const float*)d_in[26],
             *gw_W2=(const float*)d_in[27], *gw_b2=(const float*)d_in[28];
  const float* gt_W1=(const float*)d_in[29], *gt_b1=(const float*)d_in[30],
             *gt_W2=(const float*)d_in[31], *gt_b2=(const float*)d_in[32];
  const float* gsp_W1=(const float*)d_in[33], *gsp_b1=(const float*)d_in[34],
             *gsp_W2=(const float*)d_in[35], *gsp_b2=(const float*)d_in[36];
  const float* md_W1=(const float*)d_in[37], *md_b1=(const float*)d_in[38],
             *md_W2=(const float*)d_in[39], *md_b2=(const float*)d_in[40];
  const float* mt_W1=(const float*)d_in[41], *mt_b1=(const float*)d_in[42],
             *mt_W2=(const float*)d_in[43], *mt_b2=(const float*)d_in[44];
  const float* gm_W1=(const float*)d_in[45], *gm_b1=(const float*)d_in[46],
             *gm_W2=(const float*)d_in[47], *gm_b2=(const float*)d_in[48];
  const int* ec = (const int*)d_in[49];
  const int* en = (const int*)d_in[50];
  (void)in_sizes; (void)n_in; (void)out_size; (void)ws_size;

  float* ws   = (float*)d_ws;
  unsigned short* WB = (unsigned short*)(ws + WS_WB);
  float* outH = (float*)d_out;
  float* outX = outH + (size_t)N_NODES*LAT;
  float* outT = outX + (size_t)N_NODES*MUL*DD;

  k_prep<<<dim3(PREP_ZB + PREP_PB + PREP_XB), dim3(256), 0, stream>>>(
      X, Wq_W,Wk_W, gv_W1,gv_W2, gs_W1,gs_W2, gw_W1,gw_W2, gt_W1,gt_W2,
      Wrs_W,Wre_W, gsp_W1,gsp_W2, md_W1,md_W2, mt_W1,mt_W2, ws);
  k1_node<<<dim3(N_NODES/16), dim3(256), 0, stream>>>(h, WB, Wq_b, Wk_b,
      gv_b1,gv_b2, gs_b1,gs_b2, ws);
  k2_edge_w<<<dim3(E_EDGES/16), dim3(256), 0, stream>>>(sph, Wtq, Wtk, ec, en, ws);
  k3_edge_t<<<dim3(E_EDGES/32), dim3(256), 0, stream>>>(t_ij, ec, en, WB,
      gw_b1,gw_b2, gt_b1,gt_b2, Wrs_b, ucp, ws, outT);
  k4_softmax<<<dim3((E_EDGES*4)/256), dim3(256), 0, stream>>>(ec, ws);
  k5_edge_gate<<<dim3(E_EDGES/32), dim3(256), 0, stream>>>(sph, ec, en, WB,
      gsp_b1,gsp_b2, md_b1,md_b2, mt_b1,mt_b2, ws);
  k6_node<<<dim3(N_NODES/4), dim3(128), 0, stream>>>(h, X, ln_g, ln_b, Wvu,
      gm_W1,gm_b1,gm_W2,gm_b2, ucp, ws, outH, outX);
}

// Round 11
// 731.987 us; speedup vs baseline: 1.0171x; 1.0140x over previous
//
#include <hip/hip_runtime.h>
#include <math.h>

#define N_NODES 20000
#define E_EDGES 160000
#define LAT 128
#define MUL 16
#define DD 9
#define TPD 48

// ---- workspace layout (float offsets) ----
#define WS_QB     ((size_t)0)
#define WS_KB     (WS_QB + (size_t)N_NODES*LAT/2)
#define WS_VB     (WS_KB + (size_t)N_NODES*LAT/2)
#define WS_SB     (WS_VB + (size_t)N_NODES*LAT/2)
#define WS_W48    (WS_SB + (size_t)N_NODES*LAT/2)         // bf16: E*48 ushorts
#define WS_SPATB  (WS_W48 + (size_t)E_EDGES*TPD)          // bf16: E*128 ushorts
#define WS_ALPHA  (WS_SPATB + (size_t)E_EDGES*LAT/2)
#define WS_ZERO   (WS_ALPHA + (size_t)E_EDGES*4)
#define WS_AMAX   WS_ZERO
#define WS_DEN    (WS_AMAX + (size_t)N_NODES*4)
#define WS_HSUM   (WS_DEN + (size_t)N_NODES*4)            // bf16: N*128 ushorts
#define WS_NDX    (WS_HSUM + (size_t)N_NODES*LAT/2)       // bf16: N*144 ushorts
#define WS_END    (WS_NDX + (size_t)N_NODES*72)
#define ZERO_CNT  (WS_END - WS_ZERO)
#define WS_WB     WS_END                                   // ushort (bf16) packed weights
#define WS_XB     (WS_WB + (size_t)145408)                 // bf16 X table: N*144 ushorts

// packed weight offsets (ushort elements)
#define WOFF_WQ   0
#define WOFF_WK   16384
#define WOFF_GV1  32768
#define WOFF_GV2  49152
#define WOFF_GS1  65536
#define WOFF_GS2  81920
#define WOFF_GW1  98304
#define WOFF_GW2  106496
#define WOFF_GT1  122880
#define WOFF_GT2  139264
#define WOFF_WRS  155648
#define WOFF_WRE  172032
#define WOFF_GSP1 188416
#define WOFF_GSP2 204800
#define WOFF_MD1  253952
#define WOFF_MD2  270336
#define WOFF_MT1  272384
#define WOFF_MT2  288768
#define WB_TOTAL  290816

// k_prep block ranges
#define PREP_ZB   11250
#define PREP_PB   1136
#define PREP_XB   5625

#define DEVI __device__ __forceinline__

typedef short short8 __attribute__((ext_vector_type(8)));
typedef float f32x4 __attribute__((ext_vector_type(4)));

DEVI float silu_f(float x){ return x / (1.f + __expf(-x)); }
DEVI unsigned int fmap(float x){ unsigned int b=__float_as_uint(x); return (b&0x80000000u)? ~b : (b|0x80000000u); }
DEVI float funmap(unsigned int u){ return (u&0x80000000u)? __uint_as_float(u&0x7fffffffu) : __uint_as_float(~u); }

// branchless RNE f32->bf16 (proven fastest; hip_bf16 header versions carry NaN-select bloat)
DEVI unsigned short f2b(float f){ unsigned int u=__float_as_uint(f); return (unsigned short)((u + 0x7fffu + ((u>>16)&1u))>>16); }
DEVI unsigned int f2b2(float lo, float hi){ return ((unsigned int)f2b(hi)<<16) | (unsigned int)f2b(lo); }
DEVI float b2f(unsigned short u){ return __uint_as_float(((unsigned int)u)<<16); }

// packed bf16x2 fire-and-forget atomic add (gfx950)
DEVI void atom_pk(unsigned short* p, unsigned int pk){
  asm volatile("global_atomic_pk_add_bf16 %0, %1, off" :: "v"(p), "v"(pk) : "memory");
}

DEVI f32x4 mfma16(short8 a, short8 b, f32x4 c){
  return __builtin_amdgcn_mfma_f32_16x16x32_bf16(a,b,c,0,0,0);
}

template<int KB>
DEVI void mm_tile2(const unsigned short* act, int strideUS, const unsigned short* Wp,
                   int ntile, int m, int quad, f32x4* acc){
  const unsigned short* wp = Wp + (size_t)ntile*KB*512 + (size_t)quad*128 + m*8;
  const unsigned short* a0 = act + m*strideUS + quad*8;
  const unsigned short* a1 = a0 + 16*strideUS;
  #pragma unroll
  for (int kb=0;kb<KB;++kb){
    short8 bfr = *(const short8*)(wp + (size_t)kb*512);
    short8 af0 = *(const short8*)(a0 + kb*32);
    short8 af1 = *(const short8*)(a1 + kb*32);
    acc[0]=mfma16(af0,bfr,acc[0]);
    acc[1]=mfma16(af1,bfr,acc[1]);
  }
}

// single m-tile, ntile 0 (for N=16 outputs)
template<int KB>
DEVI void mm_tile1(const unsigned short* act, int strideUS, const unsigned short* Wp,
                   int mtbase, int m, int quad, f32x4& acc){
  const unsigned short* wp = Wp + (size_t)quad*128 + m*8;
  const unsigned short* a0 = act + (mtbase*16+m)*strideUS + quad*8;
  #pragma unroll
  for (int kb=0;kb<KB;++kb){
    short8 bfr = *(const short8*)(wp + (size_t)kb*512);
    short8 af  = *(const short8*)(a0 + kb*32);
    acc=mfma16(af,bfr,acc);
  }
}

template<int R, int KD, int LDSTRIDE>
DEVI void mm_acc(const float* src, const float* __restrict__ W, int wstride, int t, float* acc){
  #pragma unroll 2
  for (int k=0;k<KD;k+=4){
    float4 xv[R];
    #pragma unroll
    for (int r=0;r<R;++r) xv[r] = *(const float4*)(src + r*LDSTRIDE + k);
    #pragma unroll
    for (int kk=0;kk<4;++kk){
      float wk = W[(size_t)(k+kk)*wstride + t];
      #pragma unroll
      for (int r=0;r<R;++r) acc[r] += ((const float*)&xv[r])[kk]*wk;
    }
  }
}

// ---- K_prep: fused {zero accumulators | pack weights bf16 | X -> bf16 table} ----
__global__ __launch_bounds__(256) void k_prep(
  const float* __restrict__ X,
  const float* __restrict__ Wq,const float* __restrict__ Wk,
  const float* __restrict__ gv1,const float* __restrict__ gv2,
  const float* __restrict__ gs1,const float* __restrict__ gs2,
  const float* __restrict__ gw1,const float* __restrict__ gw2,
  const float* __restrict__ gt1,const float* __restrict__ gt2,
  const float* __restrict__ Wrs,const float* __restrict__ Wre,
  const float* __restrict__ gsp1,const float* __restrict__ gsp2,
  const float* __restrict__ md1,const float* __restrict__ md2,
  const float* __restrict__ mt1,const float* __restrict__ mt2,
  float* __restrict__ ws)
{
  const int b = blockIdx.x, tid = threadIdx.x;
  if (b < PREP_ZB){
    size_t i = (size_t)b*256 + tid;
    if (i < ZERO_CNT) ws[WS_ZERO + i] = 0.f;
    return;
  }
  if (b < PREP_ZB + PREP_PB){
    int i = (b - PREP_ZB)*256 + tid;
    if (i >= WB_TOTAL) return;
    unsigned short* dst = (unsigned short*)(ws + WS_WB);
    const int off[19] = {0,16384,32768,49152,65536,81920,98304,106496,122880,139264,
                         155648,172032,188416,204800,253952,270336,272384,288768,290816};
    int mi=0;
    while (i >= off[mi+1]) ++mi;
    int li = i - off[mi];
    int N = (mi==13)?384:((mi==15||mi==17)?16:128);
    int Ksrc = (mi==6)?48:128;
    int KB = (mi==6)?2:4;
    int j = li&7; int t = li>>3;
    int n_in = t&15; t>>=4;
    int quad = t&3; t>>=2;
    int k_block = t % KB; int n_tile = t / KB;
    int k = k_block*32 + quad*8 + j;
    int n = n_tile*16 + n_in;
    const float* src;
    switch(mi){
      case 0: src=Wq; break;  case 1: src=Wk; break;
      case 2: src=gv1; break; case 3: src=gv2; break;
      case 4: src=gs1; break; case 5: src=gs2; break;
      case 6: src=gw1; break; case 7: src=gw2; break;
      case 8: src=gt1; break; case 9: src=gt2; break;
      case 10: src=Wrs; break; case 11: src=Wre; break;
      case 12: src=gsp1; break; case 13: src=gsp2; break;
      case 14: src=md1; break; case 15: src=md2; break;
      default: src=(mi==16)?mt1:mt2; break;
    }
    float v = (k < Ksrc) ? src[(size_t)k*N + n] : 0.f;
    dst[i] = f2b(v);
    return;
  }
  {
    size_t idx = (size_t)(b - PREP_ZB - PREP_PB)*256 + tid;
    if (idx < (size_t)N_NODES*72){
      float2 v = *(const float2*)(X + idx*2);
      ((unsigned int*)(ws + WS_XB))[idx] = f2b2(v.x, v.y);
    }
    return;
  }
}

// ---- K1: per-node Q,K,V(gv),S(gs) via MFMA, 32 nodes/block; outputs bf16 ----
// (R10's 16-node halving regressed: per-block weight traffic doubled while
// per-block MFMA halved — reverted to 32.)
__global__ __launch_bounds__(256) void k1_node(const float* __restrict__ h,
  const unsigned short* __restrict__ WB,
  const float* __restrict__ Wq_b,const float* __restrict__ Wk_b,
  const float* __restrict__ gv_b1,const float* __restrict__ gv_b2,
  const float* __restrict__ gs_b1,const float* __restrict__ gs_b2,
  float* __restrict__ ws)
{
  __shared__ __align__(16) unsigned short B0[32*136], B1[32*136];
  const int tid=threadIdx.x, lane=tid&63, w=tid>>6, m=lane&15, quad=lane>>4;
  const int n0=blockIdx.x*32;
  for (int idx=tid; idx<1024; idx+=256){ int r=idx>>5, c4=(idx&31)*4;
    float4 hv = *(const float4*)(h+(size_t)(n0+r)*128+c4);
    *(unsigned int*)(B0+r*136+c4)   = f2b2(hv.x,hv.y);
    *(unsigned int*)(B0+r*136+c4+2) = f2b2(hv.z,hv.w); }
  __syncthreads();
  unsigned short* Qb=(unsigned short*)(ws+WS_QB);
  unsigned short* Kb=(unsigned short*)(ws+WS_KB);
  unsigned short* Vb=(unsigned short*)(ws+WS_VB);
  unsigned short* Sb=(unsigned short*)(ws+WS_SB);
  f32x4 z4 = {0.f,0.f,0.f,0.f};
  // Q
  { f32x4 acc[2][2]={{z4,z4},{z4,z4}};
    #pragma unroll
    for(int i=0;i<2;++i) mm_tile2<4>(B0,136,WB+WOFF_WQ, w*2+i, m, quad, acc[i]);
    #pragma unroll
    for(int i=0;i<2;++i){ int col=(w*2+i)*16+m; float bv=Wq_b[col];
      #pragma unroll
      for(int mt=0;mt<2;++mt)
        #pragma unroll
        for(int r=0;r<4;++r){ int row=mt*16+quad*4+r;
          Qb[(size_t)(n0+row)*128+col]=f2b(acc[i][mt][r]+bv); } } }
  // K
  { f32x4 acc[2][2]={{z4,z4},{z4,z4}};
    #pragma unroll
    for(int i=0;i<2;++i) mm_tile2<4>(B0,136,WB+WOFF_WK, w*2+i, m, quad, acc[i]);
    #pragma unroll
    for(int i=0;i<2;++i){ int col=(w*2+i)*16+m; float bv=Wk_b[col];
      #pragma unroll
      for(int mt=0;mt<2;++mt)
        #pragma unroll
        for(int r=0;r<4;++r){ int row=mt*16+quad*4+r;
          Kb[(size_t)(n0+row)*128+col]=f2b(acc[i][mt][r]+bv); } } }
  // gv hidden
  { f32x4 acc[2][2]={{z4,z4},{z4,z4}};
    #pragma unroll
    for(int i=0;i<2;++i) mm_tile2<4>(B0,136,WB+WOFF_GV1, w*2+i, m, quad, acc[i]);
    #pragma unroll
    for(int i=0;i<2;++i){ int col=(w*2+i)*16+m; float bv=gv_b1[col];
      #pragma unroll
      for(int mt=0;mt<2;++mt)
        #pragma unroll
        for(int r=0;r<4;++r) B1[(mt*16+quad*4+r)*136+col]=f2b(silu_f(acc[i][mt][r]+bv)); } }
  __syncthreads();
  // V out
  { f32x4 acc[2][2]={{z4,z4},{z4,z4}};
    #pragma unroll
    for(int i=0;i<2;++i) mm_tile2<4>(B1,136,WB+WOFF_GV2, w*2+i, m, quad, acc[i]);
    #pragma unroll
    for(int i=0;i<2;++i){ int col=(w*2+i)*16+m; float bv=gv_b2[col];
      #pragma unroll
      for(int mt=0;mt<2;++mt)
        #pragma unroll
        for(int r=0;r<4;++r){ int row=mt*16+quad*4+r;
          Vb[(size_t)(n0+row)*128+col]=f2b(acc[i][mt][r]+bv); } } }
  __syncthreads();
  // gs hidden
  { f32x4 acc[2][2]={{z4,z4},{z4,z4}};
    #pragma unroll
    for(int i=0;i<2;++i) mm_tile2<4>(B0,136,WB+WOFF_GS1, w*2+i, m, quad, acc[i]);
    #pragma unroll
    for(int i=0;i<2;++i){ int col=(w*2+i)*16+m; float bv=gs_b1[col];
      #pragma unroll
      for(int mt=0;mt<2;++mt)
        #pragma unroll
        for(int r=0;r<4;++r) B1[(mt*16+quad*4+r)*136+col]=f2b(silu_f(acc[i][mt][r]+bv)); } }
  __syncthreads();
  // S out
  { f32x4 acc[2][2]={{z4,z4},{z4,z4}};
    #pragma unroll
    for(int i=0;i<2;++i) mm_tile2<4>(B1,136,WB+WOFF_GS2, w*2+i, m, quad, acc[i]);
    #pragma unroll
    for(int i=0;i<2;++i){ int col=(w*2+i)*16+m; float bv=gs_b2[col];
      #pragma unroll
      for(int mt=0;mt<2;++mt)
        #pragma unroll
        for(int r=0;r<4;++r){ int row=mt*16+quad*4+r;
          Sb[(size_t)(n0+row)*128+col]=f2b(acc[i][mt][r]+bv); } } }
}

// ---- K2: per-edge w (eq_linear + rejection + slice dots) — bf16 X gathers ----
__global__ __launch_bounds__(256) void k2_edge_w(
  const float* __restrict__ sph,
  const float* __restrict__ Wtq, const float* __restrict__ Wtk,
  const int* __restrict__ ec, const int* __restrict__ en, float* __restrict__ ws)
{
  __shared__ unsigned short xcb[16*144], xnb[16*144];
  __shared__ float sphL[16][9];
  __shared__ float wq[768], wkk[768];
  __shared__ int ceI[16], nbI[16];
  const int tid=threadIdx.x, e0=blockIdx.x*16;
  if (tid<16){ ceI[tid]=ec[e0+tid]; nbI[tid]=en[e0+tid]; }
  for (int idx=tid; idx<768; idx+=256){ wq[idx]=Wtq[idx]; wkk[idx]=Wtk[idx]; }
  __syncthreads();
  const unsigned short* Xb=(const unsigned short*)(ws+WS_XB);
  for (int idx=tid; idx<1152; idx+=256){ int r=idx/72, p=idx-r*72;
    *(unsigned int*)(xcb + r*144 + 2*p) = *(const unsigned int*)(Xb + (size_t)ceI[r]*144 + 2*p);
    *(unsigned int*)(xnb + r*144 + 2*p) = *(const unsigned int*)(Xb + (size_t)nbI[r]*144 + 2*p); }
  if (tid<144){ int r=tid/9,c=tid%9; sphL[r][c]=sph[(size_t)(e0+r)*9+c]; }
  __syncthreads();
  const int el=tid>>4, j=tid&15;
  float xq[9], xk[9];
  const int ss[3]={0,1,4}, se[3]={1,4,9};
  #pragma unroll
  for (int l=0;l<3;++l){
    for (int mm2=ss[l]; mm2<se[l]; ++mm2){
      float aq=0.f, ak=0.f;
      #pragma unroll
      for (int i=0;i<16;++i){
        float wql = wq[l*256 + j*16 + i], wkl = wkk[l*256 + j*16 + i];
        aq += wql*b2f(xcb[el*144 + i*9+mm2]);
        ak += wkl*b2f(xnb[el*144 + i*9+mm2]);
      }
      xq[mm2]=aq; xk[mm2]=ak;
    }
  }
  float dq=0.f, dk=0.f;
  #pragma unroll
  for (int d=0; d<9; ++d){ dq += xq[d]*sphL[el][d]; dk += xk[d]*sphL[el][d]; }
  #pragma unroll
  for (int d=0; d<9; ++d){ xq[d] -= dq*sphL[el][d]; xk[d] -= dk*sphL[el][d]; }
  const float isc[3] = {1.f, 0.5773502691896258f, 0.4472135954999579f};
  unsigned short* W48u = (unsigned short*)(ws+WS_W48);
  #pragma unroll
  for (int l=0;l<3;++l){
    float s=0.f;
    for (int mm2=ss[l]; mm2<se[l]; ++mm2) s += xq[mm2]*xk[mm2];
    W48u[(size_t)(e0+el)*TPD + l*16 + j] = f2b(s*isc[l]);
  }
}

// ---- K3: per-edge t-update + spatial + alpha via MFMA, 32 edges/block ----
__global__ __launch_bounds__(256) void k3_edge_t(
  const float* __restrict__ t_in, const int* __restrict__ ec, const int* __restrict__ en,
  const unsigned short* __restrict__ WB,
  const float* __restrict__ gw_b1,const float* __restrict__ gw_b2,
  const float* __restrict__ gt_b1,const float* __restrict__ gt_b2,
  const float* __restrict__ Wrs_b,
  const float* __restrict__ ucp, float* __restrict__ ws, float* __restrict__ outT)
{
  __shared__ __align__(16) unsigned short tin_b[32*136], hid_b[32*136];
  __shared__ int ceI[32], nbI[32];
  const int tid=threadIdx.x, lane=tid&63, w=tid>>6, m=lane&15, quad=lane>>4;
  const int e0=blockIdx.x*32;
  if (tid<32){ ceI[tid]=ec[e0+tid]; nbI[tid]=en[e0+tid]; }
  // stage t_in -> bf16 LDS
  for (int idx=tid; idx<1024; idx+=256){ int r=idx>>5, c4=(idx&31)*4;
    float4 tv = *(const float4*)(t_in+(size_t)(e0+r)*128+c4);
    *(unsigned int*)(tin_b+r*136+c4)   = f2b2(tv.x,tv.y);
    *(unsigned int*)(tin_b+r*136+c4+2) = f2b2(tv.z,tv.w); }
  // gw-input A-fragments (bf16 w48) straight to regs
  const unsigned short* W48u=(const unsigned short*)(ws+WS_W48);
  short8 wfr[2][2];
  #pragma unroll
  for (int rr=0;rr<2;++rr){
    const unsigned short* base = W48u + (size_t)(e0 + rr*16 + m)*TPD;
    wfr[rr][0] = *(const short8*)(base + quad*8);
    if (quad<2) wfr[rr][1] = *(const short8*)(base + 32 + quad*8);
    else { short8 z = {0,0,0,0,0,0,0,0}; wfr[rr][1] = z; }
  }
  __syncthreads();
  const float uc=ucp[0], co=rsqrtf(uc*uc+1.f), ucco=uc*co;
  f32x4 z4 = {0.f,0.f,0.f,0.f};
  // P1: gw hidden (K=48 padded to 64, A from regs) -> hid_b
  { f32x4 acc[2][2]={{z4,z4},{z4,z4}};
    #pragma unroll
    for(int i=0;i<2;++i){
      const unsigned short* wp = WB+WOFF_GW1 + (size_t)(w*2+i)*1024 + (size_t)quad*128 + m*8;
      #pragma unroll
      for(int kb=0;kb<2;++kb){
        short8 bfr = *(const short8*)(wp + (size_t)kb*512);
        acc[i][0]=mfma16(wfr[0][kb],bfr,acc[i][0]);
        acc[i][1]=mfma16(wfr[1][kb],bfr,acc[i][1]);
      }
    }
    #pragma unroll
    for(int i=0;i<2;++i){ int col=(w*2+i)*16+m; float bv=gw_b1[col];
      #pragma unroll
      for(int mt=0;mt<2;++mt)
        #pragma unroll
        for(int r=0;r<4;++r) hid_b[(mt*16+quad*4+r)*136+col]=f2b(silu_f(acc[i][mt][r]+bv)); } }
  __syncthreads();
  // P2: gw out -> accw (regs)
  f32x4 accw[2][2]={{z4,z4},{z4,z4}};
  #pragma unroll
  for(int i=0;i<2;++i) mm_tile2<4>(hid_b,136,WB+WOFF_GW2, w*2+i, m, quad, accw[i]);
  __syncthreads();
  // P3: gt hidden -> hid_b (overwrite, post-barrier)
  { f32x4 acc[2][2]={{z4,z4},{z4,z4}};
    #pragma unroll
    for(int i=0;i<2;++i) mm_tile2<4>(tin_b,136,WB+WOFF_GT1, w*2+i, m, quad, acc[i]);
    #pragma unroll
    for(int i=0;i<2;++i){ int col=(w*2+i)*16+m; float bv=gt_b1[col];
      #pragma unroll
      for(int mt=0;mt<2;++mt)
        #pragma unroll
        for(int r=0;r<4;++r) hid_b[(mt*16+quad*4+r)*136+col]=f2b(silu_f(acc[i][mt][r]+bv)); } }
  __syncthreads();
  // P4: gt out; dt = gw*gt; residual -> t_new (in-place into tin_b)
  { f32x4 acct[2][2]={{z4,z4},{z4,z4}};
    #pragma unroll
    for(int i=0;i<2;++i) mm_tile2<4>(hid_b,136,WB+WOFF_GT2, w*2+i, m, quad, acct[i]);
    #pragma unroll
    for(int i=0;i<2;++i){ int col=(w*2+i)*16+m; float bw=gw_b2[col], bt=gt_b2[col];
      #pragma unroll
      for(int mt=0;mt<2;++mt)
        #pragma unroll
        for(int r=0;r<4;++r){ int row=mt*16+quad*4+r;
          float dt=(accw[i][mt][r]+bw)*(acct[i][mt][r]+bt);
          float tn=co*b2f(tin_b[row*136+col]) + ucco*dt;
          tin_b[row*136+col]=f2b(tn);            // same thread owns this slot
          outT[(size_t)(e0+row)*128+col]=tn; } } }
  __syncthreads();
  unsigned short* spatB = (unsigned short*)(ws+WS_SPATB);
  // P5: spatB = (t_new@Wrs + b)  (bf16; S[nb] multiply in k5's coalesced stage)
  { f32x4 acc[2][2]={{z4,z4},{z4,z4}};
    #pragma unroll
    for(int i=0;i<2;++i) mm_tile2<4>(tin_b,136,WB+WOFF_WRS, w*2+i, m, quad, acc[i]);
    #pragma unroll
    for(int i=0;i<2;++i){ int col=(w*2+i)*16+m; float bv=Wrs_b[col];
      #pragma unroll
      for(int mt=0;mt<2;++mt)
        #pragma unroll
        for(int r=0;r<4;++r){ int row=mt*16+quad*4+r;
          spatB[(size_t)(e0+row)*128+col]=f2b(acc[i][mt][r]+bv); } } }
  // P6a: re = silu(t_new@Wre) -> hid_b (bf16; hid_b free after P4)
  { f32x4 acc[2][2]={{z4,z4},{z4,z4}};
    #pragma unroll
    for(int i=0;i<2;++i) mm_tile2<4>(tin_b,136,WB+WOFF_WRE, w*2+i, m, quad, acc[i]);
    #pragma unroll
    for(int i=0;i<2;++i){ int col=(w*2+i)*16+m;
      #pragma unroll
      for(int mt=0;mt<2;++mt)
        #pragma unroll
        for(int r=0;r<4;++r){ int row=mt*16+quad*4+r;
          hid_b[row*136+col]=f2b(silu_f(acc[i][mt][r])); } } }
  __syncthreads();
  // P6b: alpha — 8 lanes/edge, coalesced 2x16B Q/K row loads per lane
  { const unsigned short* Qb=(const unsigned short*)(ws+WS_QB);
    const unsigned short* Kb=(const unsigned short*)(ws+WS_KB);
    unsigned int* amaxu=(unsigned int*)(ws+WS_AMAX);
    const int edge = tid>>3, sub = tid&7, hh = sub>>1, half = sub&1;
    const int ce = ceI[edge], nb = nbI[edge];
    const int cb = hh*32 + half*16;
    uint4 qa0 = *(const uint4*)(Qb + (size_t)ce*128 + cb);
    uint4 qa1 = *(const uint4*)(Qb + (size_t)ce*128 + cb + 8);
    uint4 ka0 = *(const uint4*)(Kb + (size_t)nb*128 + cb);
    uint4 ka1 = *(const uint4*)(Kb + (size_t)nb*128 + cb + 8);
    const unsigned short* reL = hid_b + edge*136 + cb;
    float p = 0.f;
    #pragma unroll
    for (int j=0;j<4;++j){
      unsigned int q0=((const unsigned int*)&qa0)[j], k0=((const unsigned int*)&ka0)[j];
      unsigned int r0=*(const unsigned int*)(reL + 2*j);
      p += b2f((unsigned short)q0)*b2f((unsigned short)k0)*b2f((unsigned short)r0);
      p += b2f((unsigned short)(q0>>16))*b2f((unsigned short)(k0>>16))*b2f((unsigned short)(r0>>16));
      unsigned int q1=((const unsigned int*)&qa1)[j], k1=((const unsigned int*)&ka1)[j];
      unsigned int r1=*(const unsigned int*)(reL + 8 + 2*j);
      p += b2f((unsigned short)q1)*b2f((unsigned short)k1)*b2f((unsigned short)r1);
      p += b2f((unsigned short)(q1>>16))*b2f((unsigned short)(k1>>16))*b2f((unsigned short)(r1>>16));
    }
    p += __shfl_xor(p,1);
    if (half==0){
      float aval = p * 0.17677669529663687f; // 1/sqrt(32)
      int e=e0+edge;
      ws[WS_ALPHA+(size_t)e*4+hh]=aval;
      atomicMax(&amaxu[(size_t)ce*4+hh], fmap(aval));
    } }
}

// ---- K4: ex = exp(alpha - amax[center]); den += ex ----
__global__ __launch_bounds__(256) void k4_softmax(const int* __restrict__ ec, float* __restrict__ ws){
  int i = blockIdx.x*256 + threadIdx.x;
  if (i >= E_EDGES*4) return;
  int e = i>>2, hh = i&3;
  int c = ec[e];
  float a = ws[WS_ALPHA + i];
  const unsigned int* amaxu = (const unsigned int*)(ws + WS_AMAX);
  float am = funmap(amaxu[(size_t)c*4+hh]);
  float exv = __expf(a - am);
  ws[WS_ALPHA + i] = exv;
  atomicAdd(&ws[WS_DEN + (size_t)c*4 + hh], exv);
}

// ---- K5: per-edge gates + segment sums via MFMA, 32 edges/block (3 LDS buffers) ----
// Staging multiplies spat*S[nb] (S read coalesced alongside V). R8-proven config.
__global__ __launch_bounds__(256) void k5_edge_gate(
  const float* __restrict__ sph,
  const int* __restrict__ ec, const int* __restrict__ en,
  const unsigned short* __restrict__ WB,
  const float* __restrict__ gsp_b1,const float* __restrict__ gsp_b2,
  const float* __restrict__ md_b1,const float* __restrict__ md_b2,
  const float* __restrict__ mt_b1,const float* __restrict__ mt_b2,
  float* __restrict__ ws)
{
  __shared__ __align__(16) unsigned short A[32*136], B[32*136], C[32*136];
  __shared__ float gdL[32*16], gtL[32*16], attnL[32*4];
  __shared__ int ceI[32], nbI[32];
  const int tid=threadIdx.x, lane=tid&63, w=tid>>6, m=lane&15, quad=lane>>4;
  const int e0=blockIdx.x*32;
  if (tid<32){ ceI[tid]=ec[e0+tid]; nbI[tid]=en[e0+tid]; }
  __syncthreads();
  if (tid<128){ int r=tid>>2, hh=tid&3;
    attnL[tid] = ws[WS_ALPHA+(size_t)(e0+r)*4+hh] / ws[WS_DEN+(size_t)ceI[r]*4+hh]; }
  __syncthreads();
  const unsigned short* Vb=(const unsigned short*)(ws+WS_VB);
  const unsigned short* Sb=(const unsigned short*)(ws+WS_SB);
  const unsigned short* spatB=(const unsigned short*)(ws+WS_SPATB);
  // combined = attn*V[nb] + spat*S[nb] -> A   (all three streams row-coalesced)
  for (int idx=tid; idx<2048; idx+=256){ int r=idx>>6, c2=(idx&63)*2;
    unsigned int va = *(const unsigned int*)(Vb+(size_t)nbI[r]*128+c2);
    unsigned int sa = *(const unsigned int*)(Sb+(size_t)nbI[r]*128+c2);
    unsigned int sp = *(const unsigned int*)(spatB+(size_t)(e0+r)*128+c2);
    float a = attnL[r*4+(c2>>5)];
    float v0 = a*b2f((unsigned short)va) + b2f((unsigned short)sp)*b2f((unsigned short)sa);
    float v1 = a*b2f((unsigned short)(va>>16)) + b2f((unsigned short)(sp>>16))*b2f((unsigned short)(sa>>16));
    *(unsigned int*)(A+r*136+c2) = f2b2(v0,v1); }
  __syncthreads();
  f32x4 z4 = {0.f,0.f,0.f,0.f};
  // P1: gsp hidden A -> B
  { f32x4 acc[2][2]={{z4,z4},{z4,z4}};
    #pragma unroll
    for(int i=0;i<2;++i) mm_tile2<4>(A,136,WB+WOFF_GSP1, w*2+i, m, quad, acc[i]);
    #pragma unroll
    for(int i=0;i<2;++i){ int col=(w*2+i)*16+m; float bv=gsp_b1[col];
      #pragma unroll
      for(int mt=0;mt<2;++mt)
        #pragma unroll
        for(int r=0;r<4;++r) B[(mt*16+quad*4+r)*136+col]=f2b(silu_f(acc[i][mt][r]+bv)); } }
  __syncthreads();
  // P2: gsp out (384 cols): o_s pk atomics; o_d -> A; o_t -> C
  { f32x4 acc[3][2][2];
    #pragma unroll
    for(int g2=0;g2<3;++g2)
      #pragma unroll
      for(int i=0;i<2;++i){ acc[g2][i][0]=z4; acc[g2][i][1]=z4; }
    #pragma unroll
    for(int g2=0;g2<3;++g2)
      #pragma unroll
      for(int i=0;i<2;++i)
        mm_tile2<4>(B,136,WB+WOFF_GSP2, g2*8+w*2+i, m, quad, acc[g2][i]);
    unsigned short* hsumB=(unsigned short*)(ws+WS_HSUM);
    #pragma unroll
    for(int i=0;i<2;++i){ int col=(w*2+i)*16+m;
      float bS=gsp_b2[col], bD=gsp_b2[128+col], bT=gsp_b2[256+col];
      #pragma unroll
      for(int mt=0;mt<2;++mt)
        #pragma unroll
        for(int r=0;r<4;++r){ int row=mt*16+quad*4+r;
          float vS = acc[0][i][mt][r]+bS;
          float vO = __shfl_xor(vS,1);
          if(!(m&1)){
            atom_pk(hsumB + (size_t)ceI[row]*128 + col, f2b2(vS,vO));
          }
          A[row*136+col]=f2b(acc[1][i][mt][r]+bD);
          C[row*136+col]=f2b(acc[2][i][mt][r]+bT); } } }
  __syncthreads();
  // P3: md hidden A -> B
  { f32x4 acc[2][2]={{z4,z4},{z4,z4}};
    #pragma unroll
    for(int i=0;i<2;++i) mm_tile2<4>(A,136,WB+WOFF_MD1, w*2+i, m, quad, acc[i]);
    #pragma unroll
    for(int i=0;i<2;++i){ int col=(w*2+i)*16+m; float bv=md_b1[col];
      #pragma unroll
      for(int mt=0;mt<2;++mt)
        #pragma unroll
        for(int r=0;r<4;++r) B[(mt*16+quad*4+r)*136+col]=f2b(silu_f(acc[i][mt][r]+bv)); } }
  __syncthreads();
  // P4: mt hidden C -> A
  { f32x4 acc[2][2]={{z4,z4},{z4,z4}};
    #pragma unroll
    for(int i=0;i<2;++i) mm_tile2<4>(C,136,WB+WOFF_MT1, w*2+i, m, quad, acc[i]);
    #pragma unroll
    for(int i=0;i<2;++i){ int col=(w*2+i)*16+m; float bv=mt_b1[col];
      #pragma unroll
      for(int mt=0;mt<2;++mt)
        #pragma unroll
        for(int r=0;r<4;++r) A[(mt*16+quad*4+r)*136+col]=f2b(silu_f(acc[i][mt][r]+bv)); } }
  __syncthreads();
  // P5: gd (waves 0-1 from B), gtt (waves 2-3 from A), N=16
  { if (w<2){
      f32x4 a=z4; mm_tile1<4>(B,136,WB+WOFF_MD2, w, m, quad, a);
      #pragma unroll
      for(int r=0;r<4;++r) gdL[(w*16+quad*4+r)*16+m]=a[r]+md_b2[m];
    } else {
      f32x4 a=z4; mm_tile1<4>(A,136,WB+WOFF_MT2, w-2, m, quad, a);
      #pragma unroll
      for(int r=0;r<4;++r) gtL[((w-2)*16+quad*4+r)*16+m]=a[r]+mt_b2[m];
    } }
  __syncthreads();
  // P6: dXij packed-bf16 atomics (X from bf16 table)
  unsigned short* ndxB=(unsigned short*)(ws+WS_NDX);
  const unsigned short* Xb=(const unsigned short*)(ws+WS_XB);
  for (int idx=tid; idx<2304; idx+=256){
    int r=idx/72, p=idx-r*72; int c0=2*p, c1=c0+1;
    int mm0=c0/9, d0=c0-mm0*9;
    int mm1=c1/9, d1=c1-mm1*9;
    const float* sphE = sph + (size_t)(e0+r)*9;
    unsigned int xa = *(const unsigned int*)(Xb + (size_t)nbI[r]*144 + c0);
    float x0=b2f((unsigned short)xa), x1=b2f((unsigned short)(xa>>16));
    float v0 = gdL[r*16+mm0]*sphE[d0] + gtL[r*16+mm0]*x0;
    float v1 = gdL[r*16+mm1]*sphE[d1] + gtL[r*16+mm1]*x1;
    atom_pk(ndxB + (size_t)ceI[r]*144 + c0, f2b2(v0,v1));
  }
}

// ---- K6: node finalize (hsum/ndx bf16 accumulators) ----
__global__ __launch_bounds__(128) void k6_node(
  const float* __restrict__ h, const float* __restrict__ Xin,
  const float* __restrict__ ln_g,const float* __restrict__ ln_b,
  const float* __restrict__ Wvu,
  const float* __restrict__ gm_W1,const float* __restrict__ gm_b1,
  const float* __restrict__ gm_W2,const float* __restrict__ gm_b2,
  const float* __restrict__ ucp, const float* __restrict__ ws,
  float* __restrict__ outH, float* __restrict__ outX)
{
  __shared__ float cat[4][144], dxb[4][144], xnw[4][144], xp[4][144], hid[4][LAT];
  __shared__ float red[4][2][2], rinv[4][3], gX[4][16], wvu[256];
  const int t=threadIdx.x, n0=blockIdx.x*4;
  const unsigned short* hsumB=(const unsigned short*)(ws+WS_HSUM);
  const unsigned short* ndxB =(const unsigned short*)(ws+WS_NDX);
  const float uc=ucp[0], co=rsqrtf(uc*uc+1.f), ucco=uc*co;
  for (int idx=t; idx<256; idx+=128) wvu[idx]=Wvu[idx];
  for (int idx=t; idx<576; idx+=128){ int r=idx/144,c=idx%144; dxb[r][c]=b2f(ndxB[(size_t)(n0+r)*144+c]); }
  float xv_[4];
  #pragma unroll
  for (int r=0;r<4;++r){
    float x=b2f(hsumB[(size_t)(n0+r)*LAT+t]); xv_[r]=x;
    float s=x, ss=x*x;
    for (int off=32; off; off>>=1){ s+=__shfl_down(s,off,64); ss+=__shfl_down(ss,off,64); }
    if ((t&63)==0){ red[r][t>>6][0]=s; red[r][t>>6][1]=ss; }
  }
  __syncthreads();
  #pragma unroll
  for (int r=0;r<4;++r){
    float s=red[r][0][0]+red[r][1][0], ss=red[r][0][1]+red[r][1][1];
    float mu=s*(1.f/128.f), var=ss*(1.f/128.f)-mu*mu;
    float dh=(xv_[r]-mu)*rsqrtf(var+1e-5f)*ln_g[t]+ln_b[t];
    cat[r][t]=co*h[(size_t)(n0+r)*LAT+t]+ucco*dh;
  }
  if (t<12){
    int r=t/3, l=t-r*3;
    int s0 = (l==0)?0:((l==1)?1:4);
    int s1 = (l==0)?1:((l==1)?4:9);
    float sum=0.f;
    for (int mm2=0;mm2<16;++mm2)
      for (int d=s0;d<s1;++d){ float v=dxb[r][mm2*9+d]; sum+=v*v; }
    rinv[r][l]=rsqrtf(sum*(1.f/16.f)+1e-8f);
  }
  __syncthreads();
  for (int idx=t; idx<144; idx+=128){
    int d=idx%9; int l=(d==0)?0:((d<4)?1:2);
    #pragma unroll
    for (int r=0;r<4;++r)
      xnw[r][idx]=co*Xin[(size_t)(n0+r)*144+idx]+ucco*dxb[r][idx]*rinv[r][l];
  }
  __syncthreads();
  for (int idx=t; idx<144; idx+=128){
    int j=idx/9, i=idx-j*9;
    #pragma unroll
    for (int r=0;r<4;++r){
      float a=0.f;
      #pragma unroll
      for (int mm2=0;mm2<16;++mm2) a+=xnw[r][mm2*9+i]*wvu[mm2*16+j];
      xp[r][idx]=a;
    }
  }
  __syncthreads();
  if (t<64){ int r=t>>4, j=t&15; float s=1e-12f;
    #pragma unroll
    for (int i=0;i<9;++i){ float v=xp[r][j*9+i]; s+=v*v; }
    cat[r][128+j]=sqrtf(s); }
  __syncthreads();
  { float acc[4]; float b=gm_b1[t];
    #pragma unroll
    for(int r=0;r<4;++r)acc[r]=b;
    mm_acc<4,144,144>(&cat[0][0],gm_W1,LAT,t,acc);
    #pragma unroll
    for(int r=0;r<4;++r) hid[r][t]=silu_f(acc[r]); }
  __syncthreads();
  { float acc[4]; float b=gm_b2[t];
    #pragma unroll
    for(int r=0;r<4;++r)acc[r]=b;
    mm_acc<4,LAT,LAT>(&hid[0][0],gm_W2,144,t,acc);
    #pragma unroll
    for(int r=0;r<4;++r) outH[(size_t)(n0+r)*LAT+t]=cat[r][t]+acc[r]; }
  if (t<16){ float acc[4]; float b=gm_b2[128+t];
    #pragma unroll
    for(int r=0;r<4;++r)acc[r]=b;
    for (int k=0;k<LAT;++k){ float wk=gm_W2[(size_t)k*144+128+t];
      #pragma unroll
      for(int r=0;r<4;++r) acc[r]+=hid[r][k]*wk; }
    #pragma unroll
    for(int r=0;r<4;++r) gX[r][t]=acc[r]; }
  __syncthreads();
  for (int idx=t; idx<144; idx+=128){
    int j=idx/9;
    #pragma unroll
    for (int r=0;r<4;++r)
      outX[(size_t)(n0+r)*144+idx]=xnw[r][idx]+gX[r][j]*xp[r][idx];
  }
}

extern "C" void kernel_launch(void* const* d_in, const int* in_sizes, int n_in,
                              void* d_out, int out_size, void* d_ws, size_t ws_size,
                              hipStream_t stream)
{
  const float* h      = (const float*)d_in[0];
  const float* X      = (const float*)d_in[1];
  const float* t_ij   = (const float*)d_in[2];
  const float* sph    = (const float*)d_in[3];
  const float* ucp    = (const float*)d_in[4];
  const float* Wtq    = (const float*)d_in[5];
  const float* Wtk    = (const float*)d_in[6];
  const float* Wrs_W  = (const float*)d_in[7];
  const float* Wrs_b  = (const float*)d_in[8];
  const float* Wq_W   = (const float*)d_in[9];
  const float* Wq_b   = (const float*)d_in[10];
  const float* Wk_W   = (const float*)d_in[11];
  const float* Wk_b   = (const float*)d_in[12];
  const float* Wre_W  = (const float*)d_in[13];
  const float* ln_g   = (const float*)d_in[14];
  const float* ln_b   = (const float*)d_in[15];
  const float* Wvu    = (const float*)d_in[16];
  const float* gs_W1=(const float*)d_in[17], *gs_b1=(const float*)d_in[18],
             *gs_W2=(const float*)d_in[19], *gs_b2=(const float*)d_in[20];
  const float* gv_W1=(const float*)d_in[21], *gv_b1=(const float*)d_in[22],
             *gv_W2=(const float*)d_in[23], *gv_b2=(const float*)d_in[24];
  const float* gw_W1=(const float*)d_in[25], *gw_b1=(const float*)d_in[26],
             *gw_W2=(const float*)d_in[27], *gw_b2=(const float*)d_in[28];
  const float* gt_W1=(const float*)d_in[29], *gt_b1=(const float*)d_in[30],
             *gt_W2=(const float*)d_in[31], *gt_b2=(const float*)d_in[32];
  const float* gsp_W1=(const float*)d_in[33], *gsp_b1=(const float*)d_in[34],
             *gsp_W2=(const float*)d_in[35], *gsp_b2=(const float*)d_in[36];
  const float* md_W1=(const float*)d_in[37], *md_b1=(const float*)d_in[38],
             *md_W2=(const float*)d_in[39], *md_b2=(const float*)d_in[40];
  const float* mt_W1=(const float*)d_in[41], *mt_b1=(const float*)d_in[42],
             *mt_W2=(const float*)d_in[43], *mt_b2=(const float*)d_in[44];
  const float* gm_W1=(const float*)d_in[45], *gm_b1=(const float*)d_in[46],
             *gm_W2=(const float*)d_in[47], *gm_b2=(const float*)d_in[48];
  const int* ec = (const int*)d_in[49];
  const int* en = (const int*)d_in[50];
  (void)in_sizes; (void)n_in; (void)out_size; (void)ws_size;

  float* ws   = (float*)d_ws;
  unsigned short* WB = (unsigned short*)(ws + WS_WB);
  float* outH = (float*)d_out;
  float* outX = outH + (size_t)N_NODES*LAT;
  float* outT = outX + (size_t)N_NODES*MUL*DD;

  k_prep<<<dim3(PREP_ZB + PREP_PB + PREP_XB), dim3(256), 0, stream>>>(
      X, Wq_W,Wk_W, gv_W1,gv_W2, gs_W1,gs_W2, gw_W1,gw_W2, gt_W1,gt_W2,
      Wrs_W,Wre_W, gsp_W1,gsp_W2, md_W1,md_W2, mt_W1,mt_W2, ws);
  k1_node<<<dim3(N_NODES/32), dim3(256), 0, stream>>>(h, WB, Wq_b, Wk_b,
      gv_b1,gv_b2, gs_b1,gs_b2, ws);
  k2_edge_w<<<dim3(E_EDGES/16), dim3(256), 0, stream>>>(sph, Wtq, Wtk, ec, en, ws);
  k3_edge_t<<<dim3(E_EDGES/32), dim3(256), 0, stream>>>(t_ij, ec, en, WB,
      gw_b1,gw_b2, gt_b1,gt_b2, Wrs_b, ucp, ws, outT);
  k4_softmax<<<dim3((E_EDGES*4)/256), dim3(256), 0, stream>>>(ec, ws);
  k5_edge_gate<<<dim3(E_EDGES/32), dim3(256), 0, stream>>>(sph, ec, en, WB,
      gsp_b1,gsp_b2, md_b1,md_b2, mt_b1,mt_b2, ws);
  k6_node<<<dim3(N_NODES/4), dim3(128), 0, stream>>>(h, X, ln_g, ln_b, Wvu,
      gm_W1,gm_b1,gm_W2,gm_b2, ucp, ws, outH, outX);
}